// Round 2
// baseline (449.741 us; speedup 1.0000x reference)
//
#include <hip/hip_runtime.h>
#include <math.h>

#define BB    4
#define TT    1024
#define DD    512
#define NH    8
#define DH    64
#define BH    32          // BB*NH
#define INV_TAU 10.0f

// ---------------------------------------------------------------------------
// K1: fused QKV projection + per-head softmax(x/tau) over Dh.
// C[M=4096, N=1536] = x[4096,512] @ [wq|wk|wv]. 64x64 tiles, 16x16 threads,
// 4x4 microtile. N-tile (64) == one (tensor, head) group -> fuse softmax.
// Output layout: [B, H, T, Dh].
// ---------------------------------------------------------------------------
__global__ __launch_bounds__(256) void k_proj_softmax(
    const float* __restrict__ x, const float* __restrict__ wq,
    const float* __restrict__ wk, const float* __restrict__ wv,
    float* __restrict__ qs, float* __restrict__ ks, float* __restrict__ vs)
{
  __shared__ float Xs[16][68];
  __shared__ float Ws[16][68];
  const int tx = threadIdx.x, ty = threadIdx.y;
  const int tid = ty * 16 + tx;
  const int n0 = blockIdx.x * 64;          // 0..1535
  const int m0 = blockIdx.y * 64;          // 0..4095
  const int tensor = n0 >> 9;
  const float* Wp = (tensor == 0) ? wq : ((tensor == 1) ? wk : wv);
  float* outp = (tensor == 0) ? qs : ((tensor == 1) ? ks : vs);
  const int nc = n0 & 511;

  const int lm = tid >> 2;                 // 0..63 (X row)
  const int lk = (tid & 3) * 4;            // 0,4,8,12 (X k quad)
  const int wkr = tid >> 4;                // 0..15 (W k row)
  const int wnc = (tid & 15) * 4;          // 0..60 (W n quad)

  float acc[4][4] = {};
  for (int k0 = 0; k0 < DD; k0 += 16) {
    float4 xv = *(const float4*)&x[(size_t)(m0 + lm) * DD + k0 + lk];
    float4 wv4 = *(const float4*)&Wp[(size_t)(k0 + wkr) * DD + nc + wnc];
    Xs[lk + 0][lm] = xv.x; Xs[lk + 1][lm] = xv.y;
    Xs[lk + 2][lm] = xv.z; Xs[lk + 3][lm] = xv.w;
    *(float4*)&Ws[wkr][wnc] = wv4;
    __syncthreads();
#pragma unroll
    for (int kk = 0; kk < 16; ++kk) {
      float4 a4 = *(const float4*)&Xs[kk][ty * 4];
      float4 b4 = *(const float4*)&Ws[kk][tx * 4];
      float a[4] = {a4.x, a4.y, a4.z, a4.w};
      float b[4] = {b4.x, b4.y, b4.z, b4.w};
#pragma unroll
      for (int r = 0; r < 4; ++r)
#pragma unroll
        for (int c = 0; c < 4; ++c) acc[r][c] += a[r] * b[c];
    }
    __syncthreads();
  }

  // Softmax epilogue: rows m0+ty*4+r, 64 cols spread over 16 tx threads.
  const int h = nc >> 6;
  const int bidx = m0 >> 10;               // batch (64 | 1024 so constant/tile)
  const int trow = m0 & 1023;
#pragma unroll
  for (int r = 0; r < 4; ++r) {
    float mx = fmaxf(fmaxf(acc[r][0], acc[r][1]), fmaxf(acc[r][2], acc[r][3]));
#pragma unroll
    for (int msk = 1; msk <= 8; msk <<= 1) mx = fmaxf(mx, __shfl_xor(mx, msk, 64));
    float e0 = __expf((acc[r][0] - mx) * INV_TAU);
    float e1 = __expf((acc[r][1] - mx) * INV_TAU);
    float e2 = __expf((acc[r][2] - mx) * INV_TAU);
    float e3 = __expf((acc[r][3] - mx) * INV_TAU);
    float sm = e0 + e1 + e2 + e3;
#pragma unroll
    for (int msk = 1; msk <= 8; msk <<= 1) sm += __shfl_xor(sm, msk, 64);
    float inv = 1.0f / sm;
    float4 p = make_float4(e0 * inv, e1 * inv, e2 * inv, e3 * inv);
    int t = trow + ty * 4 + r;
    *(float4*)&outp[(((size_t)bidx * NH + h) * TT + t) * DH + tx * 4] = p;
  }
}

// ---------------------------------------------------------------------------
// K2: A[z,i,j] = sum_d q[z,i,d]*k[z,j,d], lower-triangle 64x64 tiles only.
// ---------------------------------------------------------------------------
__global__ __launch_bounds__(256) void k_qk(
    const float* __restrict__ qs, const float* __restrict__ ks,
    float* __restrict__ A)
{
  __shared__ float Qs[16][68];
  __shared__ float Ks[16][68];
  const int z = blockIdx.y;
  const int lx = blockIdx.x;               // 0..135 lower-tri tile id
  int ti = (int)((sqrtf(8.0f * lx + 1.0f) - 1.0f) * 0.5f);
  while ((ti + 1) * (ti + 2) / 2 <= lx) ++ti;
  while (ti * (ti + 1) / 2 > lx) --ti;
  const int tj = lx - ti * (ti + 1) / 2;
  const int i0 = ti * 64, j0 = tj * 64;
  const float* Qb = qs + (size_t)z * TT * DH;
  const float* Kb = ks + (size_t)z * TT * DH;
  const int tx = threadIdx.x, ty = threadIdx.y;
  const int tid = ty * 16 + tx;
  const int lm = tid >> 2, lk = (tid & 3) * 4;

  float acc[4][4] = {};
  for (int k0 = 0; k0 < DH; k0 += 16) {
    float4 qv = *(const float4*)&Qb[(size_t)(i0 + lm) * DH + k0 + lk];
    float4 kv = *(const float4*)&Kb[(size_t)(j0 + lm) * DH + k0 + lk];
    Qs[lk + 0][lm] = qv.x; Qs[lk + 1][lm] = qv.y;
    Qs[lk + 2][lm] = qv.z; Qs[lk + 3][lm] = qv.w;
    Ks[lk + 0][lm] = kv.x; Ks[lk + 1][lm] = kv.y;
    Ks[lk + 2][lm] = kv.z; Ks[lk + 3][lm] = kv.w;
    __syncthreads();
#pragma unroll
    for (int kk = 0; kk < 16; ++kk) {
      float4 a4 = *(const float4*)&Qs[kk][ty * 4];
      float4 b4 = *(const float4*)&Ks[kk][tx * 4];
      float a[4] = {a4.x, a4.y, a4.z, a4.w};
      float b[4] = {b4.x, b4.y, b4.z, b4.w};
#pragma unroll
      for (int r = 0; r < 4; ++r)
#pragma unroll
        for (int c = 0; c < 4; ++c) acc[r][c] += a[r] * b[c];
    }
    __syncthreads();
  }

  float* Ab = A + (size_t)z * TT * TT;
#pragma unroll
  for (int r = 0; r < 4; ++r) {
    const int i = i0 + ty * 4 + r;
    const int jb = j0 + tx * 4;
    if (ti != tj) {
      float4 v = make_float4(acc[r][0], acc[r][1], acc[r][2], acc[r][3]);
      *(float4*)&Ab[(size_t)i * TT + jb] = v;
    } else {
#pragma unroll
      for (int c = 0; c < 4; ++c)
        if (jb + c <= i) Ab[(size_t)i * TT + jb + c] = acc[r][c];
    }
  }
}

// ---------------------------------------------------------------------------
// K3: run-length scan along diagonals, in place.
// For diagonal d: s_i = A[i, i-d]; cs = prefix-sum(s);
// m = prefix-max(cs*(1-s)); out = cs - m. One thread per diagonal;
// contiguous addresses across lanes at each step.
//
// Latency-bound sequential chain -> depth-4 rotating register prefetch:
// loads for batch b+3 issue before computing batch b (24 loads in flight).
// Outer loop unrolled x4 so buffer indices stay compile-time constants
// (dynamic indexing of a register array would spill to scratch).
// ---------------------------------------------------------------------------
__global__ __launch_bounds__(64) void k_scan(float* __restrict__ A)
{
  const int z = blockIdx.y;
  const int dbase = blockIdx.x * 64;
  const int d = dbase + threadIdx.x;
  float* __restrict__ Ab = A + (size_t)z * TT * TT;
  const int nb = (TT - dbase) >> 3;        // 8-row batches; multiple of 8
  float buf[4][8];

#define LOAD_BATCH(q, slot)                                                  \
  {                                                                          \
    const int r0_ = dbase + (q) * 8;                                         \
    _Pragma("unroll")                                                        \
    for (int u = 0; u < 8; ++u) {                                            \
      int i_ = r0_ + u;                                                      \
      size_t idx_ = (i_ >= d) ? ((size_t)i_ * (TT + 1) - d) : 0;             \
      float v_ = Ab[idx_];                                                   \
      buf[slot][u] = (i_ >= d) ? v_ : 0.0f;                                  \
    }                                                                        \
  }

  LOAD_BATCH(0, 0);
  if (nb > 1) LOAD_BATCH(1, 1);
  if (nb > 2) LOAD_BATCH(2, 2);

  float cs = 0.0f, m = 0.0f;

#define STEP(b, slot, lslot)                                                 \
  {                                                                          \
    if ((b) + 3 < nb) LOAD_BATCH((b) + 3, lslot);                            \
    float o_[8];                                                             \
    _Pragma("unroll")                                                        \
    for (int u = 0; u < 8; ++u) {                                            \
      cs += buf[slot][u];                                                    \
      float g_ = cs * (1.0f - buf[slot][u]);                                 \
      m = fmaxf(m, g_);                                                      \
      o_[u] = cs - m;                                                        \
    }                                                                        \
    const int r0_ = dbase + (b) * 8;                                         \
    _Pragma("unroll")                                                        \
    for (int u = 0; u < 8; ++u) {                                            \
      int i_ = r0_ + u;                                                      \
      if (i_ >= d) Ab[(size_t)i_ * (TT + 1) - d] = o_[u];                    \
    }                                                                        \
  }

  for (int bb = 0; bb < nb; bb += 4) {
    STEP(bb + 0, 0, 3);
    STEP(bb + 1, 1, 0);
    STEP(bb + 2, 2, 1);
    STEP(bb + 3, 3, 2);
  }
#undef STEP
#undef LOAD_BATCH
}

// ---------------------------------------------------------------------------
// K4: row softmax (with positional tie-break, /tau). Writes unnormalized
// exp back into A and the row sum to rowsum[].
// ---------------------------------------------------------------------------
__global__ __launch_bounds__(256) void k_rowsoftmax(
    float* __restrict__ A, float* __restrict__ rowsum)
{
  const int row = blockIdx.x;              // 0..BH*TT-1
  const int i = row & (TT - 1);
  const int tid = threadIdx.x;
  float* __restrict__ Ar = A + (size_t)row * TT;
  const float inv_i1 = 1.0f / (float)(i + 1);

  float v[4];
  float mx = -1e30f;
#pragma unroll
  for (int u = 0; u < 4; ++u) {
    int j = u * 256 + tid;
    if (j <= i) {
      v[u] = Ar[j] + (float)j * inv_i1;
      mx = fmaxf(mx, v[u]);
    } else {
      v[u] = -1e30f;
    }
  }
#pragma unroll
  for (int msk = 1; msk <= 32; msk <<= 1) mx = fmaxf(mx, __shfl_xor(mx, msk, 64));
  __shared__ float redm[4];
  __shared__ float reds[4];
  const int wid = tid >> 6, lid = tid & 63;
  if (lid == 0) redm[wid] = mx;
  __syncthreads();
  mx = fmaxf(fmaxf(redm[0], redm[1]), fmaxf(redm[2], redm[3]));

  float sm = 0.0f;
#pragma unroll
  for (int u = 0; u < 4; ++u) {
    int j = u * 256 + tid;
    if (j <= i) {
      float e = __expf((v[u] - mx) * INV_TAU);
      Ar[j] = e;
      sm += e;
    }
  }
#pragma unroll
  for (int msk = 1; msk <= 32; msk <<= 1) sm += __shfl_xor(sm, msk, 64);
  if (lid == 0) reds[wid] = sm;
  __syncthreads();
  if (tid == 0) rowsum[row] = reds[0] + reds[1] + reds[2] + reds[3];
}

// ---------------------------------------------------------------------------
// K5: O[z,i,d] = (sum_{j<=i} P[z,i,j] * V[z,j,d]) / rowsum[z,i]
// ---------------------------------------------------------------------------
__global__ __launch_bounds__(256) void k_pv(
    const float* __restrict__ A, const float* __restrict__ vs,
    const float* __restrict__ rowsum, float* __restrict__ oatt)
{
  __shared__ float Ps[16][68];
  __shared__ float Vs[16][68];
  const int z = blockIdx.y, ti = blockIdx.x;
  const int i0 = ti * 64;
  const float* Ab = A + (size_t)z * TT * TT;
  const float* Vb = vs + (size_t)z * TT * DH;
  const int tx = threadIdx.x, ty = threadIdx.y;
  const int tid = ty * 16 + tx;
  const int lm = tid >> 2, lk = (tid & 3) * 4;   // P loader
  const int vk = tid >> 4, vn = (tid & 15) * 4;  // V loader

  float acc[4][4] = {};
  const int jend = i0 + 64;
  for (int j0 = 0; j0 < jend; j0 += 16) {
    const int irow = i0 + lm;
    const float* src = &Ab[(size_t)irow * TT + j0 + lk];
    float p0 = (j0 + lk + 0 <= irow) ? src[0] : 0.0f;
    float p1 = (j0 + lk + 1 <= irow) ? src[1] : 0.0f;
    float p2 = (j0 + lk + 2 <= irow) ? src[2] : 0.0f;
    float p3 = (j0 + lk + 3 <= irow) ? src[3] : 0.0f;
    Ps[lk + 0][lm] = p0; Ps[lk + 1][lm] = p1;
    Ps[lk + 2][lm] = p2; Ps[lk + 3][lm] = p3;
    *(float4*)&Vs[vk][vn] = *(const float4*)&Vb[(size_t)(j0 + vk) * DH + vn];
    __syncthreads();
#pragma unroll
    for (int kk = 0; kk < 16; ++kk) {
      float4 a4 = *(const float4*)&Ps[kk][ty * 4];
      float4 b4 = *(const float4*)&Vs[kk][tx * 4];
      float a[4] = {a4.x, a4.y, a4.z, a4.w};
      float b[4] = {b4.x, b4.y, b4.z, b4.w};
#pragma unroll
      for (int r = 0; r < 4; ++r)
#pragma unroll
        for (int c = 0; c < 4; ++c) acc[r][c] += a[r] * b[c];
    }
    __syncthreads();
  }

#pragma unroll
  for (int r = 0; r < 4; ++r) {
    const int i = i0 + ty * 4 + r;
    const float inv = 1.0f / rowsum[(size_t)z * TT + i];
    float4 v = make_float4(acc[r][0] * inv, acc[r][1] * inv,
                           acc[r][2] * inv, acc[r][3] * inv);
    *(float4*)&oatt[((size_t)z * TT + i) * DH + tx * 4] = v;
  }
}

// ---------------------------------------------------------------------------
// K6: per-head output projection.
// out[b, t, h*64+e] = sum_d oatt[b,h,t,d] * wo[(h*64+d)*64 + e]
// ---------------------------------------------------------------------------
__global__ __launch_bounds__(256) void k_oproj(
    const float* __restrict__ oatt, const float* __restrict__ wo,
    float* __restrict__ out)
{
  __shared__ float Wl[64][64];
  __shared__ float Ol[4][64];
  const int z = blockIdx.y;                // b*NH + h
  const int t0 = blockIdx.x * 4;
  const int b = z >> 3, h = z & 7;
  const int tid = threadIdx.x;
  const float* wb = wo + (size_t)h * 64 * 64;
#pragma unroll
  for (int u = 0; u < 4; ++u) {
    int q = tid + 256 * u;                 // float4 index 0..1023
    int dd = q >> 4, e4 = (q & 15) * 4;
    *(float4*)&Wl[dd][e4] = *(const float4*)&wb[(size_t)dd * 64 + e4];
  }
  {
    int r = tid >> 6, dd = tid & 63;
    Ol[r][dd] = oatt[((size_t)z * TT + t0 + r) * DH + dd];
  }
  __syncthreads();
  const int r = tid >> 6, e = tid & 63;
  float acc = 0.0f;
#pragma unroll
  for (int d = 0; d < 64; ++d) acc += Ol[r][d] * Wl[d][e];
  out[((size_t)b * TT + t0 + r) * DD + h * 64 + e] = acc;
}

// ---------------------------------------------------------------------------
extern "C" void kernel_launch(void* const* d_in, const int* in_sizes, int n_in,
                              void* d_out, int out_size, void* d_ws, size_t ws_size,
                              hipStream_t stream)
{
  (void)in_sizes; (void)n_in; (void)out_size; (void)ws_size;
  const float* x  = (const float*)d_in[0];
  const float* wq = (const float*)d_in[1];
  const float* wk = (const float*)d_in[2];
  const float* wv = (const float*)d_in[3];
  const float* wo = (const float*)d_in[4];
  float* out = (float*)d_out;

  char* ws = (char*)d_ws;
  float* qs     = (float*)(ws);                                  // 8 MB
  float* ks     = (float*)(ws + (size_t)8  * 1024 * 1024);       // 8 MB
  float* vs     = (float*)(ws + (size_t)16 * 1024 * 1024);       // 8 MB
  float* oatt   = (float*)(ws + (size_t)24 * 1024 * 1024);       // 8 MB
  float* rowsum = (float*)(ws + (size_t)32 * 1024 * 1024);       // 128 KB
  float* A      = (float*)(ws + (size_t)33 * 1024 * 1024);       // 128 MB

  hipLaunchKernelGGL(k_proj_softmax, dim3(24, 64), dim3(16, 16), 0, stream,
                     x, wq, wk, wv, qs, ks, vs);
  hipLaunchKernelGGL(k_qk, dim3(136, BH), dim3(16, 16), 0, stream, qs, ks, A);
  hipLaunchKernelGGL(k_scan, dim3(TT / 64, BH), dim3(64), 0, stream, A);
  hipLaunchKernelGGL(k_rowsoftmax, dim3(BH * TT), dim3(256), 0, stream, A, rowsum);
  hipLaunchKernelGGL(k_pv, dim3(TT / 64, BH), dim3(16, 16), 0, stream,
                     A, vs, rowsum, oatt);
  hipLaunchKernelGGL(k_oproj, dim3(TT / 4, BH), dim3(256), 0, stream,
                     oatt, wo, out);
}

// Round 3
// 412.787 us; speedup vs baseline: 1.0895x; 1.0895x over previous
//
#include <hip/hip_runtime.h>
#include <math.h>

#define BB    4
#define TT    1024
#define DD    512
#define NH    8
#define DH    64
#define BH    32          // BB*NH
#define INV_TAU 10.0f

// ---------------------------------------------------------------------------
// K1: fused QKV projection + per-head softmax(x/tau) over Dh.
// C[M=4096, N=1536] = x[4096,512] @ [wq|wk|wv]. 64x64 tiles, 16x16 threads,
// 4x4 microtile. N-tile (64) == one (tensor, head) group -> fuse softmax.
// Output layout: [B, H, T, Dh].
// ---------------------------------------------------------------------------
__global__ __launch_bounds__(256) void k_proj_softmax(
    const float* __restrict__ x, const float* __restrict__ wq,
    const float* __restrict__ wk, const float* __restrict__ wv,
    float* __restrict__ qs, float* __restrict__ ks, float* __restrict__ vs)
{
  __shared__ float Xs[16][68];
  __shared__ float Ws[16][68];
  const int tx = threadIdx.x, ty = threadIdx.y;
  const int tid = ty * 16 + tx;
  const int n0 = blockIdx.x * 64;          // 0..1535
  const int m0 = blockIdx.y * 64;          // 0..4095
  const int tensor = n0 >> 9;
  const float* Wp = (tensor == 0) ? wq : ((tensor == 1) ? wk : wv);
  float* outp = (tensor == 0) ? qs : ((tensor == 1) ? ks : vs);
  const int nc = n0 & 511;

  const int lm = tid >> 2;                 // 0..63 (X row)
  const int lk = (tid & 3) * 4;            // 0,4,8,12 (X k quad)
  const int wkr = tid >> 4;                // 0..15 (W k row)
  const int wnc = (tid & 15) * 4;          // 0..60 (W n quad)

  float acc[4][4] = {};
  for (int k0 = 0; k0 < DD; k0 += 16) {
    float4 xv = *(const float4*)&x[(size_t)(m0 + lm) * DD + k0 + lk];
    float4 wv4 = *(const float4*)&Wp[(size_t)(k0 + wkr) * DD + nc + wnc];
    Xs[lk + 0][lm] = xv.x; Xs[lk + 1][lm] = xv.y;
    Xs[lk + 2][lm] = xv.z; Xs[lk + 3][lm] = xv.w;
    *(float4*)&Ws[wkr][wnc] = wv4;
    __syncthreads();
#pragma unroll
    for (int kk = 0; kk < 16; ++kk) {
      float4 a4 = *(const float4*)&Xs[kk][ty * 4];
      float4 b4 = *(const float4*)&Ws[kk][tx * 4];
      float a[4] = {a4.x, a4.y, a4.z, a4.w};
      float b[4] = {b4.x, b4.y, b4.z, b4.w};
#pragma unroll
      for (int r = 0; r < 4; ++r)
#pragma unroll
        for (int c = 0; c < 4; ++c) acc[r][c] += a[r] * b[c];
    }
    __syncthreads();
  }

  // Softmax epilogue: rows m0+ty*4+r, 64 cols spread over 16 tx threads.
  const int h = nc >> 6;
  const int bidx = m0 >> 10;               // batch (64 | 1024 so constant/tile)
  const int trow = m0 & 1023;
#pragma unroll
  for (int r = 0; r < 4; ++r) {
    float mx = fmaxf(fmaxf(acc[r][0], acc[r][1]), fmaxf(acc[r][2], acc[r][3]));
#pragma unroll
    for (int msk = 1; msk <= 8; msk <<= 1) mx = fmaxf(mx, __shfl_xor(mx, msk, 64));
    float e0 = __expf((acc[r][0] - mx) * INV_TAU);
    float e1 = __expf((acc[r][1] - mx) * INV_TAU);
    float e2 = __expf((acc[r][2] - mx) * INV_TAU);
    float e3 = __expf((acc[r][3] - mx) * INV_TAU);
    float sm = e0 + e1 + e2 + e3;
#pragma unroll
    for (int msk = 1; msk <= 8; msk <<= 1) sm += __shfl_xor(sm, msk, 64);
    float inv = 1.0f / sm;
    float4 p = make_float4(e0 * inv, e1 * inv, e2 * inv, e3 * inv);
    int t = trow + ty * 4 + r;
    *(float4*)&outp[(((size_t)bidx * NH + h) * TT + t) * DH + tx * 4] = p;
  }
}

// ---------------------------------------------------------------------------
// K2: A[z,i,j] = sum_d q[z,i,d]*k[z,j,d], lower-triangle 64x64 tiles only.
// ---------------------------------------------------------------------------
__global__ __launch_bounds__(256) void k_qk(
    const float* __restrict__ qs, const float* __restrict__ ks,
    float* __restrict__ A)
{
  __shared__ float Qs[16][68];
  __shared__ float Ks[16][68];
  const int z = blockIdx.y;
  const int lx = blockIdx.x;               // 0..135 lower-tri tile id
  int ti = (int)((sqrtf(8.0f * lx + 1.0f) - 1.0f) * 0.5f);
  while ((ti + 1) * (ti + 2) / 2 <= lx) ++ti;
  while (ti * (ti + 1) / 2 > lx) --ti;
  const int tj = lx - ti * (ti + 1) / 2;
  const int i0 = ti * 64, j0 = tj * 64;
  const float* Qb = qs + (size_t)z * TT * DH;
  const float* Kb = ks + (size_t)z * TT * DH;
  const int tx = threadIdx.x, ty = threadIdx.y;
  const int tid = ty * 16 + tx;
  const int lm = tid >> 2, lk = (tid & 3) * 4;

  float acc[4][4] = {};
  for (int k0 = 0; k0 < DH; k0 += 16) {
    float4 qv = *(const float4*)&Qb[(size_t)(i0 + lm) * DH + k0 + lk];
    float4 kv = *(const float4*)&Kb[(size_t)(j0 + lm) * DH + k0 + lk];
    Qs[lk + 0][lm] = qv.x; Qs[lk + 1][lm] = qv.y;
    Qs[lk + 2][lm] = qv.z; Qs[lk + 3][lm] = qv.w;
    Ks[lk + 0][lm] = kv.x; Ks[lk + 1][lm] = kv.y;
    Ks[lk + 2][lm] = kv.z; Ks[lk + 3][lm] = kv.w;
    __syncthreads();
#pragma unroll
    for (int kk = 0; kk < 16; ++kk) {
      float4 a4 = *(const float4*)&Qs[kk][ty * 4];
      float4 b4 = *(const float4*)&Ks[kk][tx * 4];
      float a[4] = {a4.x, a4.y, a4.z, a4.w};
      float b[4] = {b4.x, b4.y, b4.z, b4.w};
#pragma unroll
      for (int r = 0; r < 4; ++r)
#pragma unroll
        for (int c = 0; c < 4; ++c) acc[r][c] += a[r] * b[c];
    }
    __syncthreads();
  }

  float* Ab = A + (size_t)z * TT * TT;
#pragma unroll
  for (int r = 0; r < 4; ++r) {
    const int i = i0 + ty * 4 + r;
    const int jb = j0 + tx * 4;
    if (ti != tj) {
      float4 v = make_float4(acc[r][0], acc[r][1], acc[r][2], acc[r][3]);
      *(float4*)&Ab[(size_t)i * TT + jb] = v;
    } else {
#pragma unroll
      for (int c = 0; c < 4; ++c)
        if (jb + c <= i) Ab[(size_t)i * TT + jb + c] = acc[r][c];
    }
  }
}

// ---------------------------------------------------------------------------
// K3: run-length scan along diagonals, in place — chunked-parallel version.
// Per diagonal d: s_i = A[i,i-d]; cs = prefix-sum(s); m = prefix-max(cs*(1-s));
// out = cs - m.  Decomposition: once a chunk's incoming prefix sum cs_in is
// known, its g_k = (cs_in + lcs_k)*(1-s_k) are fully determined. So:
//   A: per-chunk sums (parallel, store-free -> loads pipeline)
//   B: cross-chunk exclusive prefix-sum (LDS, 8 chunks)
//   C: per-chunk max of g (parallel, store-free)
//   D: cross-chunk prefix-max (LDS)
//   E: final in-chunk sequential emit (short chain, TLP-hidden)
// Block: 512 thr = 8 waves; wave w = row chunk w; lane = diagonal.
// 4096 waves total (16/CU) vs 512 before.  m init 0 is safe: s in [0,1]
// (dot of softmax vectors) => g = cs*(1-s) >= 0.
// ---------------------------------------------------------------------------
__global__ __launch_bounds__(512) void k_scan(float* __restrict__ A)
{
  __shared__ float Ssum[8][64];
  __shared__ float Gmax[8][64];
  const int z = blockIdx.y;
  const int dbase = blockIdx.x * 64;
  const int lane = threadIdx.x & 63;
  const int w = threadIdx.x >> 6;          // chunk id 0..7 (wave-uniform)
  const int d = dbase + lane;
  float* __restrict__ Ab = A + (size_t)z * TT * TT;
  const int R = TT - dbase;                // rows this group scans
  const int L = R >> 3;                    // rows per chunk (multiple of 8)
  const int r0 = dbase + w * L;

  // Phase A: chunk sum
  float S = 0.0f;
#pragma unroll 8
  for (int t = 0; t < L; ++t) {
    int i = r0 + t;
    size_t idx = (i >= d) ? ((size_t)i * (TT + 1) - d) : 0;
    float s0 = Ab[idx];
    S += (i >= d) ? s0 : 0.0f;
  }
  Ssum[w][lane] = S;
  __syncthreads();

  // Phase B: exclusive prefix-sum of chunk sums
  float cs_in = 0.0f;
  for (int ww = 0; ww < w; ++ww) cs_in += Ssum[ww][lane];

  // Phase C: chunk max of g
  float lcs = 0.0f, gm = 0.0f;
#pragma unroll 8
  for (int t = 0; t < L; ++t) {
    int i = r0 + t;
    size_t idx = (i >= d) ? ((size_t)i * (TT + 1) - d) : 0;
    float s0 = Ab[idx];
    float s = (i >= d) ? s0 : 0.0f;
    lcs += s;
    float cs = cs_in + lcs;
    gm = fmaxf(gm, cs * (1.0f - s));
  }
  Gmax[w][lane] = gm;
  __syncthreads();

  // Phase D: exclusive prefix-max
  float m = 0.0f;
  for (int ww = 0; ww < w; ++ww) m = fmaxf(m, Gmax[ww][lane]);

  // Phase E: final emit
  lcs = 0.0f;
#pragma unroll 8
  for (int t = 0; t < L; ++t) {
    int i = r0 + t;
    bool ok = (i >= d);
    size_t idx = ok ? ((size_t)i * (TT + 1) - d) : 0;
    float s0 = Ab[idx];
    float s = ok ? s0 : 0.0f;
    lcs += s;
    float cs = cs_in + lcs;
    m = fmaxf(m, cs * (1.0f - s));
    if (ok) Ab[idx] = cs - m;
  }
}

// ---------------------------------------------------------------------------
// K4: row softmax (with positional tie-break, /tau). Writes unnormalized
// exp back into A and the row sum to rowsum[].
// ---------------------------------------------------------------------------
__global__ __launch_bounds__(256) void k_rowsoftmax(
    float* __restrict__ A, float* __restrict__ rowsum)
{
  const int row = blockIdx.x;              // 0..BH*TT-1
  const int i = row & (TT - 1);
  const int tid = threadIdx.x;
  float* __restrict__ Ar = A + (size_t)row * TT;
  const float inv_i1 = 1.0f / (float)(i + 1);

  float v[4];
  float mx = -1e30f;
#pragma unroll
  for (int u = 0; u < 4; ++u) {
    int j = u * 256 + tid;
    if (j <= i) {
      v[u] = Ar[j] + (float)j * inv_i1;
      mx = fmaxf(mx, v[u]);
    } else {
      v[u] = -1e30f;
    }
  }
#pragma unroll
  for (int msk = 1; msk <= 32; msk <<= 1) mx = fmaxf(mx, __shfl_xor(mx, msk, 64));
  __shared__ float redm[4];
  __shared__ float reds[4];
  const int wid = tid >> 6, lid = tid & 63;
  if (lid == 0) redm[wid] = mx;
  __syncthreads();
  mx = fmaxf(fmaxf(redm[0], redm[1]), fmaxf(redm[2], redm[3]));

  float sm = 0.0f;
#pragma unroll
  for (int u = 0; u < 4; ++u) {
    int j = u * 256 + tid;
    if (j <= i) {
      float e = __expf((v[u] - mx) * INV_TAU);
      Ar[j] = e;
      sm += e;
    }
  }
#pragma unroll
  for (int msk = 1; msk <= 32; msk <<= 1) sm += __shfl_xor(sm, msk, 64);
  if (lid == 0) reds[wid] = sm;
  __syncthreads();
  if (tid == 0) rowsum[row] = reds[0] + reds[1] + reds[2] + reds[3];
}

// ---------------------------------------------------------------------------
// K5: O[z,i,d] = (sum_{j<=i} P[z,i,j] * V[z,j,d]) / rowsum[z,i]
// ---------------------------------------------------------------------------
__global__ __launch_bounds__(256) void k_pv(
    const float* __restrict__ A, const float* __restrict__ vs,
    const float* __restrict__ rowsum, float* __restrict__ oatt)
{
  __shared__ float Ps[16][68];
  __shared__ float Vs[16][68];
  const int z = blockIdx.y, ti = blockIdx.x;
  const int i0 = ti * 64;
  const float* Ab = A + (size_t)z * TT * TT;
  const float* Vb = vs + (size_t)z * TT * DH;
  const int tx = threadIdx.x, ty = threadIdx.y;
  const int tid = ty * 16 + tx;
  const int lm = tid >> 2, lk = (tid & 3) * 4;   // P loader
  const int vk = tid >> 4, vn = (tid & 15) * 4;  // V loader

  float acc[4][4] = {};
  const int jend = i0 + 64;
  for (int j0 = 0; j0 < jend; j0 += 16) {
    const int irow = i0 + lm;
    const float* src = &Ab[(size_t)irow * TT + j0 + lk];
    float p0 = (j0 + lk + 0 <= irow) ? src[0] : 0.0f;
    float p1 = (j0 + lk + 1 <= irow) ? src[1] : 0.0f;
    float p2 = (j0 + lk + 2 <= irow) ? src[2] : 0.0f;
    float p3 = (j0 + lk + 3 <= irow) ? src[3] : 0.0f;
    Ps[lk + 0][lm] = p0; Ps[lk + 1][lm] = p1;
    Ps[lk + 2][lm] = p2; Ps[lk + 3][lm] = p3;
    *(float4*)&Vs[vk][vn] = *(const float4*)&Vb[(size_t)(j0 + vk) * DH + vn];
    __syncthreads();
#pragma unroll
    for (int kk = 0; kk < 16; ++kk) {
      float4 a4 = *(const float4*)&Ps[kk][ty * 4];
      float4 b4 = *(const float4*)&Vs[kk][tx * 4];
      float a[4] = {a4.x, a4.y, a4.z, a4.w};
      float b[4] = {b4.x, b4.y, b4.z, b4.w};
#pragma unroll
      for (int r = 0; r < 4; ++r)
#pragma unroll
        for (int c = 0; c < 4; ++c) acc[r][c] += a[r] * b[c];
    }
    __syncthreads();
  }

#pragma unroll
  for (int r = 0; r < 4; ++r) {
    const int i = i0 + ty * 4 + r;
    const float inv = 1.0f / rowsum[(size_t)z * TT + i];
    float4 v = make_float4(acc[r][0] * inv, acc[r][1] * inv,
                           acc[r][2] * inv, acc[r][3] * inv);
    *(float4*)&oatt[((size_t)z * TT + i) * DH + tx * 4] = v;
  }
}

// ---------------------------------------------------------------------------
// K6: per-head output projection.
// out[b, t, h*64+e] = sum_d oatt[b,h,t,d] * wo[(h*64+d)*64 + e]
// ---------------------------------------------------------------------------
__global__ __launch_bounds__(256) void k_oproj(
    const float* __restrict__ oatt, const float* __restrict__ wo,
    float* __restrict__ out)
{
  __shared__ float Wl[64][64];
  __shared__ float Ol[4][64];
  const int z = blockIdx.y;                // b*NH + h
  const int t0 = blockIdx.x * 4;
  const int b = z >> 3, h = z & 7;
  const int tid = threadIdx.x;
  const float* wb = wo + (size_t)h * 64 * 64;
#pragma unroll
  for (int u = 0; u < 4; ++u) {
    int q = tid + 256 * u;                 // float4 index 0..1023
    int dd = q >> 4, e4 = (q & 15) * 4;
    *(float4*)&Wl[dd][e4] = *(const float4*)&wb[(size_t)dd * 64 + e4];
  }
  {
    int r = tid >> 6, dd = tid & 63;
    Ol[r][dd] = oatt[((size_t)z * TT + t0 + r) * DH + dd];
  }
  __syncthreads();
  const int r = tid >> 6, e = tid & 63;
  float acc = 0.0f;
#pragma unroll
  for (int d = 0; d < 64; ++d) acc += Ol[r][d] * Wl[d][e];
  out[((size_t)b * TT + t0 + r) * DD + h * 64 + e] = acc;
}

// ---------------------------------------------------------------------------
extern "C" void kernel_launch(void* const* d_in, const int* in_sizes, int n_in,
                              void* d_out, int out_size, void* d_ws, size_t ws_size,
                              hipStream_t stream)
{
  (void)in_sizes; (void)n_in; (void)out_size; (void)ws_size;
  const float* x  = (const float*)d_in[0];
  const float* wq = (const float*)d_in[1];
  const float* wk = (const float*)d_in[2];
  const float* wv = (const float*)d_in[3];
  const float* wo = (const float*)d_in[4];
  float* out = (float*)d_out;

  char* ws = (char*)d_ws;
  float* qs     = (float*)(ws);                                  // 8 MB
  float* ks     = (float*)(ws + (size_t)8  * 1024 * 1024);       // 8 MB
  float* vs     = (float*)(ws + (size_t)16 * 1024 * 1024);       // 8 MB
  float* oatt   = (float*)(ws + (size_t)24 * 1024 * 1024);       // 8 MB
  float* rowsum = (float*)(ws + (size_t)32 * 1024 * 1024);       // 128 KB
  float* A      = (float*)(ws + (size_t)33 * 1024 * 1024);       // 128 MB

  hipLaunchKernelGGL(k_proj_softmax, dim3(24, 64), dim3(16, 16), 0, stream,
                     x, wq, wk, wv, qs, ks, vs);
  hipLaunchKernelGGL(k_qk, dim3(136, BH), dim3(16, 16), 0, stream, qs, ks, A);
  hipLaunchKernelGGL(k_scan, dim3(TT / 64, BH), dim3(512), 0, stream, A);
  hipLaunchKernelGGL(k_rowsoftmax, dim3(BH * TT), dim3(256), 0, stream, A, rowsum);
  hipLaunchKernelGGL(k_pv, dim3(TT / 64, BH), dim3(16, 16), 0, stream,
                     A, vs, rowsum, oatt);
  hipLaunchKernelGGL(k_oproj, dim3(TT / 4, BH), dim3(256), 0, stream,
                     oatt, wo, out);
}

// Round 4
// 361.451 us; speedup vs baseline: 1.2443x; 1.1420x over previous
//
#include <hip/hip_runtime.h>
#include <math.h>

#define BB    4
#define TT    1024
#define DD    512
#define NH    8
#define DH    64
#define BH    32          // BB*NH
#define INV_TAU 10.0f

typedef __attribute__((ext_vector_type(8))) short short8;
typedef __attribute__((ext_vector_type(4))) float f4;

__device__ inline unsigned short f2bf(float f) {
  unsigned u = __float_as_uint(f);
  u += 0x7FFFu + ((u >> 16) & 1u);        // round-to-nearest-even
  return (unsigned short)(u >> 16);
}
__device__ inline float bf2f(unsigned short h) {
  return __uint_as_float(((unsigned)h) << 16);
}

// ---------------------------------------------------------------------------
// P1: split x (fp32 [4096][512]) into bf16 hi/lo planes (same layout).
// ---------------------------------------------------------------------------
__global__ __launch_bounds__(256) void k_split_x(
    const float* __restrict__ x, unsigned short* __restrict__ xh,
    unsigned short* __restrict__ xl)
{
  const int i = (blockIdx.x * 256 + threadIdx.x) * 4;
  float4 v = *(const float4*)&x[i];
  ushort4 h, l;
  h.x = f2bf(v.x); l.x = f2bf(v.x - bf2f(h.x));
  h.y = f2bf(v.y); l.y = f2bf(v.y - bf2f(h.y));
  h.z = f2bf(v.z); l.z = f2bf(v.z - bf2f(h.z));
  h.w = f2bf(v.w); l.w = f2bf(v.w - bf2f(h.w));
  *(ushort4*)&xh[i] = h;
  *(ushort4*)&xl[i] = l;
}

// ---------------------------------------------------------------------------
// P2: transpose + split W. Input wq/wk/wv each [K=512][N=512] fp32.
// Output wth/wtl [1536][512] bf16: row = ten*512 + n, col = k (k-consecutive
// so MFMA B-fragments load as contiguous 16B).
// ---------------------------------------------------------------------------
__global__ __launch_bounds__(256) void k_split_wt(
    const float* __restrict__ wq, const float* __restrict__ wk,
    const float* __restrict__ wv, unsigned short* __restrict__ wth,
    unsigned short* __restrict__ wtl)
{
  __shared__ float Wf[64][65];
  const int ten = blockIdx.z;
  const float* W = (ten == 0) ? wq : ((ten == 1) ? wk : wv);
  const int n0 = blockIdx.x * 64, k0 = blockIdx.y * 64;
  const int tid = threadIdx.x;
#pragma unroll
  for (int p = 0; p < 4; ++p) {
    int kk = p * 16 + (tid >> 4);
    int nn = (tid & 15) * 4;
    float4 v = *(const float4*)&W[(size_t)(k0 + kk) * 512 + n0 + nn];
    Wf[kk][nn + 0] = v.x; Wf[kk][nn + 1] = v.y;
    Wf[kk][nn + 2] = v.z; Wf[kk][nn + 3] = v.w;
  }
  __syncthreads();
  const int n = tid >> 2, kq = tid & 3;    // 16 k's per thread
  size_t base = ((size_t)(ten * 512 + n0 + n)) * 512 + k0 + kq * 16;
#pragma unroll
  for (int jj = 0; jj < 4; ++jj) {
    ushort4 h, l;
    float f0 = Wf[kq * 16 + jj * 4 + 0][n];
    float f1 = Wf[kq * 16 + jj * 4 + 1][n];
    float f2 = Wf[kq * 16 + jj * 4 + 2][n];
    float f3 = Wf[kq * 16 + jj * 4 + 3][n];
    h.x = f2bf(f0); l.x = f2bf(f0 - bf2f(h.x));
    h.y = f2bf(f1); l.y = f2bf(f1 - bf2f(h.y));
    h.z = f2bf(f2); l.z = f2bf(f2 - bf2f(h.z));
    h.w = f2bf(f3); l.w = f2bf(f3 - bf2f(h.w));
    *(ushort4*)&wth[base + jj * 4] = h;
    *(ushort4*)&wtl[base + jj * 4] = l;
  }
}

// ---------------------------------------------------------------------------
// K1: QKV projection via bf16x3 MFMA + fused per-head softmax.
// C[4096,1536] = x @ [wq|wk|wv], split-precision: Ah*Bh + Ah*Bl + Al*Bh.
// Block: 128x128 tile, 4 waves in 2x2, each wave 64x64 (16 MFMA tiles).
// 16x16x32 bf16 MFMA; fragments: A[m=lane&15][k=quad*8+j], B[n=lane&15][k],
// D col=lane&15, row=quad*4+reg (verified layouts).
// Epilogue: row softmax over the wave's 64-col head group -> qs/ks/vs
// in [B,H,T,Dh] fp32.
// ---------------------------------------------------------------------------
__global__ __launch_bounds__(256) void k_proj_mfma(
    const unsigned short* __restrict__ xh, const unsigned short* __restrict__ xl,
    const unsigned short* __restrict__ wth, const unsigned short* __restrict__ wtl,
    float* __restrict__ qs, float* __restrict__ ks, float* __restrict__ vs)
{
  __shared__ unsigned short Ah[128][40];   // 40-ushort (80B) stride: 16B-aligned,
  __shared__ unsigned short Al[128][40];   // 2-way banks (free)
  __shared__ unsigned short Bh[128][40];
  __shared__ unsigned short Bl[128][40];
  const int tid = threadIdx.x;
  const int n0g = blockIdx.x * 128;        // 0..1408
  const int m0 = blockIdx.y * 128;
  const int w = tid >> 6, lane = tid & 63;
  const int mw = (w & 1) * 64, nw = (w >> 1) * 64;
  const int quad = lane >> 4, l16 = lane & 15;
  const int srow = tid >> 2;               // 0..63 staging row
  const int sk = (tid & 3) * 8;            // 0,8,16,24 staging k offset

  f4 acc[4][4] = {};

  for (int k0 = 0; k0 < DD; k0 += 32) {
    short8 a0 = *(const short8*)&xh[(size_t)(m0 + srow) * DD + k0 + sk];
    short8 a1 = *(const short8*)&xh[(size_t)(m0 + 64 + srow) * DD + k0 + sk];
    short8 a2 = *(const short8*)&xl[(size_t)(m0 + srow) * DD + k0 + sk];
    short8 a3 = *(const short8*)&xl[(size_t)(m0 + 64 + srow) * DD + k0 + sk];
    short8 b0 = *(const short8*)&wth[(size_t)(n0g + srow) * DD + k0 + sk];
    short8 b1 = *(const short8*)&wth[(size_t)(n0g + 64 + srow) * DD + k0 + sk];
    short8 b2 = *(const short8*)&wtl[(size_t)(n0g + srow) * DD + k0 + sk];
    short8 b3 = *(const short8*)&wtl[(size_t)(n0g + 64 + srow) * DD + k0 + sk];
    *(short8*)&Ah[srow][sk] = a0;  *(short8*)&Ah[64 + srow][sk] = a1;
    *(short8*)&Al[srow][sk] = a2;  *(short8*)&Al[64 + srow][sk] = a3;
    *(short8*)&Bh[srow][sk] = b0;  *(short8*)&Bh[64 + srow][sk] = b1;
    *(short8*)&Bl[srow][sk] = b2;  *(short8*)&Bl[64 + srow][sk] = b3;
    __syncthreads();

    short8 fbh[4], fbl[4];
#pragma unroll
    for (int nt = 0; nt < 4; ++nt) {
      fbh[nt] = *(const short8*)&Bh[nw + nt * 16 + l16][quad * 8];
      fbl[nt] = *(const short8*)&Bl[nw + nt * 16 + l16][quad * 8];
    }
#pragma unroll
    for (int mt = 0; mt < 4; ++mt) {
      short8 fah = *(const short8*)&Ah[mw + mt * 16 + l16][quad * 8];
      short8 fal = *(const short8*)&Al[mw + mt * 16 + l16][quad * 8];
#pragma unroll
      for (int nt = 0; nt < 4; ++nt) {
        acc[mt][nt] = __builtin_amdgcn_mfma_f32_16x16x32_bf16(fah, fbh[nt], acc[mt][nt], 0, 0, 0);
        acc[mt][nt] = __builtin_amdgcn_mfma_f32_16x16x32_bf16(fah, fbl[nt], acc[mt][nt], 0, 0, 0);
        acc[mt][nt] = __builtin_amdgcn_mfma_f32_16x16x32_bf16(fal, fbh[nt], acc[mt][nt], 0, 0, 0);
      }
    }
    __syncthreads();
  }

  // Epilogue: softmax over the wave's 64-col head group.
  const int tensor = n0g >> 9;
  float* outp = (tensor == 0) ? qs : ((tensor == 1) ? ks : vs);
  const int ncol = (n0g & 511) + nw;       // multiple of 64
  const int h = ncol >> 6;
#pragma unroll
  for (int mt = 0; mt < 4; ++mt) {
#pragma unroll
    for (int r = 0; r < 4; ++r) {
      float v0 = acc[mt][0][r], v1 = acc[mt][1][r];
      float v2 = acc[mt][2][r], v3 = acc[mt][3][r];
      float mx = fmaxf(fmaxf(v0, v1), fmaxf(v2, v3));
#pragma unroll
      for (int msk = 1; msk <= 8; msk <<= 1) mx = fmaxf(mx, __shfl_xor(mx, msk, 64));
      float e0 = __expf((v0 - mx) * INV_TAU);
      float e1 = __expf((v1 - mx) * INV_TAU);
      float e2 = __expf((v2 - mx) * INV_TAU);
      float e3 = __expf((v3 - mx) * INV_TAU);
      float sm = e0 + e1 + e2 + e3;
#pragma unroll
      for (int msk = 1; msk <= 8; msk <<= 1) sm += __shfl_xor(sm, msk, 64);
      float inv = 1.0f / sm;
      int row = m0 + mw + mt * 16 + quad * 4 + r;
      int b = row >> 10, t = row & 1023;
      float* dst = &outp[(((size_t)b * NH + h) * TT + t) * DH];
      dst[l16 + 0]  = e0 * inv;
      dst[l16 + 16] = e1 * inv;
      dst[l16 + 32] = e2 * inv;
      dst[l16 + 48] = e3 * inv;
    }
  }
}

// ---------------------------------------------------------------------------
// K2: A[z,i,j] = sum_d q[z,i,d]*k[z,j,d], lower-triangle 64x64 tiles only.
// ---------------------------------------------------------------------------
__global__ __launch_bounds__(256) void k_qk(
    const float* __restrict__ qs, const float* __restrict__ ks,
    float* __restrict__ A)
{
  __shared__ float Qs[16][68];
  __shared__ float Ks[16][68];
  const int z = blockIdx.y;
  const int lx = blockIdx.x;               // 0..135 lower-tri tile id
  int ti = (int)((sqrtf(8.0f * lx + 1.0f) - 1.0f) * 0.5f);
  while ((ti + 1) * (ti + 2) / 2 <= lx) ++ti;
  while (ti * (ti + 1) / 2 > lx) --ti;
  const int tj = lx - ti * (ti + 1) / 2;
  const int i0 = ti * 64, j0 = tj * 64;
  const float* Qb = qs + (size_t)z * TT * DH;
  const float* Kb = ks + (size_t)z * TT * DH;
  const int tx = threadIdx.x, ty = threadIdx.y;
  const int tid = ty * 16 + tx;
  const int lm = tid >> 2, lk = (tid & 3) * 4;

  float acc[4][4] = {};
  for (int k0 = 0; k0 < DH; k0 += 16) {
    float4 qv = *(const float4*)&Qb[(size_t)(i0 + lm) * DH + k0 + lk];
    float4 kv = *(const float4*)&Kb[(size_t)(j0 + lm) * DH + k0 + lk];
    Qs[lk + 0][lm] = qv.x; Qs[lk + 1][lm] = qv.y;
    Qs[lk + 2][lm] = qv.z; Qs[lk + 3][lm] = qv.w;
    Ks[lk + 0][lm] = kv.x; Ks[lk + 1][lm] = kv.y;
    Ks[lk + 2][lm] = kv.z; Ks[lk + 3][lm] = kv.w;
    __syncthreads();
#pragma unroll
    for (int kk = 0; kk < 16; ++kk) {
      float4 a4 = *(const float4*)&Qs[kk][ty * 4];
      float4 b4 = *(const float4*)&Ks[kk][tx * 4];
      float a[4] = {a4.x, a4.y, a4.z, a4.w};
      float b[4] = {b4.x, b4.y, b4.z, b4.w};
#pragma unroll
      for (int r = 0; r < 4; ++r)
#pragma unroll
        for (int c = 0; c < 4; ++c) acc[r][c] += a[r] * b[c];
    }
    __syncthreads();
  }

  float* Ab = A + (size_t)z * TT * TT;
#pragma unroll
  for (int r = 0; r < 4; ++r) {
    const int i = i0 + ty * 4 + r;
    const int jb = j0 + tx * 4;
    if (ti != tj) {
      float4 v = make_float4(acc[r][0], acc[r][1], acc[r][2], acc[r][3]);
      *(float4*)&Ab[(size_t)i * TT + jb] = v;
    } else {
#pragma unroll
      for (int c = 0; c < 4; ++c)
        if (jb + c <= i) Ab[(size_t)i * TT + jb + c] = acc[r][c];
    }
  }
}

// ---------------------------------------------------------------------------
// K3: run-length scan along diagonals, chunked-parallel (see R3 notes).
// ---------------------------------------------------------------------------
__global__ __launch_bounds__(512) void k_scan(float* __restrict__ A)
{
  __shared__ float Ssum[8][64];
  __shared__ float Gmax[8][64];
  const int z = blockIdx.y;
  const int dbase = blockIdx.x * 64;
  const int lane = threadIdx.x & 63;
  const int w = threadIdx.x >> 6;
  const int d = dbase + lane;
  float* __restrict__ Ab = A + (size_t)z * TT * TT;
  const int R = TT - dbase;
  const int L = R >> 3;
  const int r0 = dbase + w * L;

  float S = 0.0f;
#pragma unroll 8
  for (int t = 0; t < L; ++t) {
    int i = r0 + t;
    size_t idx = (i >= d) ? ((size_t)i * (TT + 1) - d) : 0;
    float s0 = Ab[idx];
    S += (i >= d) ? s0 : 0.0f;
  }
  Ssum[w][lane] = S;
  __syncthreads();

  float cs_in = 0.0f;
  for (int ww = 0; ww < w; ++ww) cs_in += Ssum[ww][lane];

  float lcs = 0.0f, gm = 0.0f;
#pragma unroll 8
  for (int t = 0; t < L; ++t) {
    int i = r0 + t;
    size_t idx = (i >= d) ? ((size_t)i * (TT + 1) - d) : 0;
    float s0 = Ab[idx];
    float s = (i >= d) ? s0 : 0.0f;
    lcs += s;
    float cs = cs_in + lcs;
    gm = fmaxf(gm, cs * (1.0f - s));
  }
  Gmax[w][lane] = gm;
  __syncthreads();

  float m = 0.0f;
  for (int ww = 0; ww < w; ++ww) m = fmaxf(m, Gmax[ww][lane]);

  lcs = 0.0f;
#pragma unroll 8
  for (int t = 0; t < L; ++t) {
    int i = r0 + t;
    bool ok = (i >= d);
    size_t idx = ok ? ((size_t)i * (TT + 1) - d) : 0;
    float s0 = Ab[idx];
    float s = ok ? s0 : 0.0f;
    lcs += s;
    float cs = cs_in + lcs;
    m = fmaxf(m, cs * (1.0f - s));
    if (ok) Ab[idx] = cs - m;
  }
}

// ---------------------------------------------------------------------------
// K4: row softmax (positional tie-break, /tau). Unnormalized exp + row sums.
// ---------------------------------------------------------------------------
__global__ __launch_bounds__(256) void k_rowsoftmax(
    float* __restrict__ A, float* __restrict__ rowsum)
{
  const int row = blockIdx.x;
  const int i = row & (TT - 1);
  const int tid = threadIdx.x;
  float* __restrict__ Ar = A + (size_t)row * TT;
  const float inv_i1 = 1.0f / (float)(i + 1);

  float v[4];
  float mx = -1e30f;
#pragma unroll
  for (int u = 0; u < 4; ++u) {
    int j = u * 256 + tid;
    if (j <= i) {
      v[u] = Ar[j] + (float)j * inv_i1;
      mx = fmaxf(mx, v[u]);
    } else {
      v[u] = -1e30f;
    }
  }
#pragma unroll
  for (int msk = 1; msk <= 32; msk <<= 1) mx = fmaxf(mx, __shfl_xor(mx, msk, 64));
  __shared__ float redm[4];
  __shared__ float reds[4];
  const int wid = tid >> 6, lid = tid & 63;
  if (lid == 0) redm[wid] = mx;
  __syncthreads();
  mx = fmaxf(fmaxf(redm[0], redm[1]), fmaxf(redm[2], redm[3]));

  float sm = 0.0f;
#pragma unroll
  for (int u = 0; u < 4; ++u) {
    int j = u * 256 + tid;
    if (j <= i) {
      float e = __expf((v[u] - mx) * INV_TAU);
      Ar[j] = e;
      sm += e;
    }
  }
#pragma unroll
  for (int msk = 1; msk <= 32; msk <<= 1) sm += __shfl_xor(sm, msk, 64);
  if (lid == 0) reds[wid] = sm;
  __syncthreads();
  if (tid == 0) rowsum[row] = reds[0] + reds[1] + reds[2] + reds[3];
}

// ---------------------------------------------------------------------------
// K5: O[z,i,d] = (sum_{j<=i} P[z,i,j] * V[z,j,d]) / rowsum[z,i]
// ---------------------------------------------------------------------------
__global__ __launch_bounds__(256) void k_pv(
    const float* __restrict__ A, const float* __restrict__ vs,
    const float* __restrict__ rowsum, float* __restrict__ oatt)
{
  __shared__ float Ps[16][68];
  __shared__ float Vs[16][68];
  const int z = blockIdx.y, ti = blockIdx.x;
  const int i0 = ti * 64;
  const float* Ab = A + (size_t)z * TT * TT;
  const float* Vb = vs + (size_t)z * TT * DH;
  const int tx = threadIdx.x, ty = threadIdx.y;
  const int tid = ty * 16 + tx;
  const int lm = tid >> 2, lk = (tid & 3) * 4;   // P loader
  const int vk = tid >> 4, vn = (tid & 15) * 4;  // V loader

  float acc[4][4] = {};
  const int jend = i0 + 64;
  for (int j0 = 0; j0 < jend; j0 += 16) {
    const int irow = i0 + lm;
    const float* src = &Ab[(size_t)irow * TT + j0 + lk];
    float p0 = (j0 + lk + 0 <= irow) ? src[0] : 0.0f;
    float p1 = (j0 + lk + 1 <= irow) ? src[1] : 0.0f;
    float p2 = (j0 + lk + 2 <= irow) ? src[2] : 0.0f;
    float p3 = (j0 + lk + 3 <= irow) ? src[3] : 0.0f;
    Ps[lk + 0][lm] = p0; Ps[lk + 1][lm] = p1;
    Ps[lk + 2][lm] = p2; Ps[lk + 3][lm] = p3;
    *(float4*)&Vs[vk][vn] = *(const float4*)&Vb[(size_t)(j0 + vk) * DH + vn];
    __syncthreads();
#pragma unroll
    for (int kk = 0; kk < 16; ++kk) {
      float4 a4 = *(const float4*)&Ps[kk][ty * 4];
      float4 b4 = *(const float4*)&Vs[kk][tx * 4];
      float a[4] = {a4.x, a4.y, a4.z, a4.w};
      float b[4] = {b4.x, b4.y, b4.z, b4.w};
#pragma unroll
      for (int r = 0; r < 4; ++r)
#pragma unroll
        for (int c = 0; c < 4; ++c) acc[r][c] += a[r] * b[c];
    }
    __syncthreads();
  }

#pragma unroll
  for (int r = 0; r < 4; ++r) {
    const int i = i0 + ty * 4 + r;
    const float inv = 1.0f / rowsum[(size_t)z * TT + i];
    float4 v = make_float4(acc[r][0] * inv, acc[r][1] * inv,
                           acc[r][2] * inv, acc[r][3] * inv);
    *(float4*)&oatt[((size_t)z * TT + i) * DH + tx * 4] = v;
  }
}

// ---------------------------------------------------------------------------
// K6: per-head output projection.
// ---------------------------------------------------------------------------
__global__ __launch_bounds__(256) void k_oproj(
    const float* __restrict__ oatt, const float* __restrict__ wo,
    float* __restrict__ out)
{
  __shared__ float Wl[64][64];
  __shared__ float Ol[4][64];
  const int z = blockIdx.y;                // b*NH + h
  const int t0 = blockIdx.x * 4;
  const int b = z >> 3, h = z & 7;
  const int tid = threadIdx.x;
  const float* wb = wo + (size_t)h * 64 * 64;
#pragma unroll
  for (int u = 0; u < 4; ++u) {
    int q = tid + 256 * u;
    int dd = q >> 4, e4 = (q & 15) * 4;
    *(float4*)&Wl[dd][e4] = *(const float4*)&wb[(size_t)dd * 64 + e4];
  }
  {
    int r = tid >> 6, dd = tid & 63;
    Ol[r][dd] = oatt[((size_t)z * TT + t0 + r) * DH + dd];
  }
  __syncthreads();
  const int r = tid >> 6, e = tid & 63;
  float acc = 0.0f;
#pragma unroll
  for (int d = 0; d < 64; ++d) acc += Ol[r][d] * Wl[d][e];
  out[((size_t)b * TT + t0 + r) * DD + h * 64 + e] = acc;
}

// ---------------------------------------------------------------------------
extern "C" void kernel_launch(void* const* d_in, const int* in_sizes, int n_in,
                              void* d_out, int out_size, void* d_ws, size_t ws_size,
                              hipStream_t stream)
{
  (void)in_sizes; (void)n_in; (void)out_size; (void)ws_size;
  const float* x  = (const float*)d_in[0];
  const float* wq = (const float*)d_in[1];
  const float* wk = (const float*)d_in[2];
  const float* wv = (const float*)d_in[3];
  const float* wo = (const float*)d_in[4];
  float* out = (float*)d_out;

  char* ws = (char*)d_ws;
  float* qs     = (float*)(ws);                                  // 8 MB
  float* ks     = (float*)(ws + (size_t)8  * 1024 * 1024);       // 8 MB
  float* vs     = (float*)(ws + (size_t)16 * 1024 * 1024);       // 8 MB
  // xh/xl live in the oatt slot (dead before k_pv writes oatt)
  unsigned short* xh = (unsigned short*)(ws + (size_t)24 * 1024 * 1024);  // 4 MB
  unsigned short* xl = (unsigned short*)(ws + (size_t)28 * 1024 * 1024);  // 4 MB
  float* oatt   = (float*)(ws + (size_t)24 * 1024 * 1024);       // 8 MB (after proj)
  float* rowsum = (float*)(ws + (size_t)32 * 1024 * 1024);       // 128 KB
  float* A      = (float*)(ws + (size_t)33 * 1024 * 1024);       // 128 MB
  unsigned short* wth = (unsigned short*)(ws + (size_t)161 * 1024 * 1024); // 1.6 MB
  unsigned short* wtl = (unsigned short*)(ws + (size_t)163 * 1024 * 1024); // 1.6 MB

  hipLaunchKernelGGL(k_split_x, dim3(2048), dim3(256), 0, stream, x, xh, xl);
  hipLaunchKernelGGL(k_split_wt, dim3(8, 8, 3), dim3(256), 0, stream,
                     wq, wk, wv, wth, wtl);
  hipLaunchKernelGGL(k_proj_mfma, dim3(12, 32), dim3(256), 0, stream,
                     xh, xl, wth, wtl, qs, ks, vs);
  hipLaunchKernelGGL(k_qk, dim3(136, BH), dim3(16, 16), 0, stream, qs, ks, A);
  hipLaunchKernelGGL(k_scan, dim3(TT / 64, BH), dim3(512), 0, stream, A);
  hipLaunchKernelGGL(k_rowsoftmax, dim3(BH * TT), dim3(256), 0, stream, A, rowsum);
  hipLaunchKernelGGL(k_pv, dim3(TT / 64, BH), dim3(16, 16), 0, stream,
                     A, vs, rowsum, oatt);
  hipLaunchKernelGGL(k_oproj, dim3(TT / 4, BH), dim3(256), 0, stream,
                     oatt, wo, out);
}

// Round 5
// 279.195 us; speedup vs baseline: 1.6109x; 1.2946x over previous
//
#include <hip/hip_runtime.h>
#include <math.h>

#define BB    4
#define TT    1024
#define DD    512
#define NH    8
#define DH    64
#define BH    32          // BB*NH
#define INV_TAU 10.0f

typedef __attribute__((ext_vector_type(8))) short short8;
typedef __attribute__((ext_vector_type(4))) float f4;

__device__ inline unsigned short f2bf(float f) {
  unsigned u = __float_as_uint(f);
  u += 0x7FFFu + ((u >> 16) & 1u);        // round-to-nearest-even
  return (unsigned short)(u >> 16);
}
__device__ inline float bf2f(unsigned short h) {
  return __uint_as_float(((unsigned)h) << 16);
}

// ---------------------------------------------------------------------------
// P1: split x (fp32 [4096][512]) into bf16 hi/lo planes (same layout).
// ---------------------------------------------------------------------------
__global__ __launch_bounds__(256) void k_split_x(
    const float* __restrict__ x, unsigned short* __restrict__ xh,
    unsigned short* __restrict__ xl)
{
  const int i = (blockIdx.x * 256 + threadIdx.x) * 4;
  float4 v = *(const float4*)&x[i];
  ushort4 h, l;
  h.x = f2bf(v.x); l.x = f2bf(v.x - bf2f(h.x));
  h.y = f2bf(v.y); l.y = f2bf(v.y - bf2f(h.y));
  h.z = f2bf(v.z); l.z = f2bf(v.z - bf2f(h.z));
  h.w = f2bf(v.w); l.w = f2bf(v.w - bf2f(h.w));
  *(ushort4*)&xh[i] = h;
  *(ushort4*)&xl[i] = l;
}

// ---------------------------------------------------------------------------
// P2: transpose + split W -> wth/wtl [1536][512] bf16, k-contiguous rows.
// ---------------------------------------------------------------------------
__global__ __launch_bounds__(256) void k_split_wt(
    const float* __restrict__ wq, const float* __restrict__ wk,
    const float* __restrict__ wv, unsigned short* __restrict__ wth,
    unsigned short* __restrict__ wtl)
{
  __shared__ float Wf[64][65];
  const int ten = blockIdx.z;
  const float* W = (ten == 0) ? wq : ((ten == 1) ? wk : wv);
  const int n0 = blockIdx.x * 64, k0 = blockIdx.y * 64;
  const int tid = threadIdx.x;
#pragma unroll
  for (int p = 0; p < 4; ++p) {
    int kk = p * 16 + (tid >> 4);
    int nn = (tid & 15) * 4;
    float4 v = *(const float4*)&W[(size_t)(k0 + kk) * 512 + n0 + nn];
    Wf[kk][nn + 0] = v.x; Wf[kk][nn + 1] = v.y;
    Wf[kk][nn + 2] = v.z; Wf[kk][nn + 3] = v.w;
  }
  __syncthreads();
  const int n = tid >> 2, kq = tid & 3;
  size_t base = ((size_t)(ten * 512 + n0 + n)) * 512 + k0 + kq * 16;
#pragma unroll
  for (int jj = 0; jj < 4; ++jj) {
    ushort4 h, l;
    float f0 = Wf[kq * 16 + jj * 4 + 0][n];
    float f1 = Wf[kq * 16 + jj * 4 + 1][n];
    float f2 = Wf[kq * 16 + jj * 4 + 2][n];
    float f3 = Wf[kq * 16 + jj * 4 + 3][n];
    h.x = f2bf(f0); l.x = f2bf(f0 - bf2f(h.x));
    h.y = f2bf(f1); l.y = f2bf(f1 - bf2f(h.y));
    h.z = f2bf(f2); l.z = f2bf(f2 - bf2f(h.z));
    h.w = f2bf(f3); l.w = f2bf(f3 - bf2f(h.w));
    *(ushort4*)&wth[base + jj * 4] = h;
    *(ushort4*)&wtl[base + jj * 4] = l;
  }
}

// ---------------------------------------------------------------------------
// K1: QKV projection via bf16x3 MFMA + fused per-head softmax.
// q,k heads: emitted as bf16 hi/lo planes [z][t][d] (feeds MFMA qk).
// v heads:  emitted fp32 [z][t][d] (k_vsplit transposes+splits for pv).
// ---------------------------------------------------------------------------
__global__ __launch_bounds__(256) void k_proj_mfma(
    const unsigned short* __restrict__ xh, const unsigned short* __restrict__ xl,
    const unsigned short* __restrict__ wth, const unsigned short* __restrict__ wtl,
    unsigned short* __restrict__ qh, unsigned short* __restrict__ ql,
    unsigned short* __restrict__ kh, unsigned short* __restrict__ kl,
    float* __restrict__ vs)
{
  __shared__ unsigned short Ah[128][40];
  __shared__ unsigned short Al[128][40];
  __shared__ unsigned short Bh[128][40];
  __shared__ unsigned short Bl[128][40];
  const int tid = threadIdx.x;
  const int n0g = blockIdx.x * 128;
  const int m0 = blockIdx.y * 128;
  const int w = tid >> 6, lane = tid & 63;
  const int mw = (w & 1) * 64, nw = (w >> 1) * 64;
  const int quad = lane >> 4, l16 = lane & 15;
  const int srow = tid >> 2;
  const int sk = (tid & 3) * 8;

  f4 acc[4][4] = {};

  for (int k0 = 0; k0 < DD; k0 += 32) {
    short8 a0 = *(const short8*)&xh[(size_t)(m0 + srow) * DD + k0 + sk];
    short8 a1 = *(const short8*)&xh[(size_t)(m0 + 64 + srow) * DD + k0 + sk];
    short8 a2 = *(const short8*)&xl[(size_t)(m0 + srow) * DD + k0 + sk];
    short8 a3 = *(const short8*)&xl[(size_t)(m0 + 64 + srow) * DD + k0 + sk];
    short8 b0 = *(const short8*)&wth[(size_t)(n0g + srow) * DD + k0 + sk];
    short8 b1 = *(const short8*)&wth[(size_t)(n0g + 64 + srow) * DD + k0 + sk];
    short8 b2 = *(const short8*)&wtl[(size_t)(n0g + srow) * DD + k0 + sk];
    short8 b3 = *(const short8*)&wtl[(size_t)(n0g + 64 + srow) * DD + k0 + sk];
    *(short8*)&Ah[srow][sk] = a0;  *(short8*)&Ah[64 + srow][sk] = a1;
    *(short8*)&Al[srow][sk] = a2;  *(short8*)&Al[64 + srow][sk] = a3;
    *(short8*)&Bh[srow][sk] = b0;  *(short8*)&Bh[64 + srow][sk] = b1;
    *(short8*)&Bl[srow][sk] = b2;  *(short8*)&Bl[64 + srow][sk] = b3;
    __syncthreads();

    short8 fbh[4], fbl[4];
#pragma unroll
    for (int nt = 0; nt < 4; ++nt) {
      fbh[nt] = *(const short8*)&Bh[nw + nt * 16 + l16][quad * 8];
      fbl[nt] = *(const short8*)&Bl[nw + nt * 16 + l16][quad * 8];
    }
#pragma unroll
    for (int mt = 0; mt < 4; ++mt) {
      short8 fah = *(const short8*)&Ah[mw + mt * 16 + l16][quad * 8];
      short8 fal = *(const short8*)&Al[mw + mt * 16 + l16][quad * 8];
#pragma unroll
      for (int nt = 0; nt < 4; ++nt) {
        acc[mt][nt] = __builtin_amdgcn_mfma_f32_16x16x32_bf16(fah, fbh[nt], acc[mt][nt], 0, 0, 0);
        acc[mt][nt] = __builtin_amdgcn_mfma_f32_16x16x32_bf16(fah, fbl[nt], acc[mt][nt], 0, 0, 0);
        acc[mt][nt] = __builtin_amdgcn_mfma_f32_16x16x32_bf16(fal, fbh[nt], acc[mt][nt], 0, 0, 0);
      }
    }
    __syncthreads();
  }

  const int tensor = n0g >> 9;
  const int ncol = (n0g & 511) + nw;
  const int h = ncol >> 6;
#pragma unroll
  for (int mt = 0; mt < 4; ++mt) {
#pragma unroll
    for (int r = 0; r < 4; ++r) {
      float v0 = acc[mt][0][r], v1 = acc[mt][1][r];
      float v2 = acc[mt][2][r], v3 = acc[mt][3][r];
      float mx = fmaxf(fmaxf(v0, v1), fmaxf(v2, v3));
#pragma unroll
      for (int msk = 1; msk <= 8; msk <<= 1) mx = fmaxf(mx, __shfl_xor(mx, msk, 64));
      float e0 = __expf((v0 - mx) * INV_TAU);
      float e1 = __expf((v1 - mx) * INV_TAU);
      float e2 = __expf((v2 - mx) * INV_TAU);
      float e3 = __expf((v3 - mx) * INV_TAU);
      float sm = e0 + e1 + e2 + e3;
#pragma unroll
      for (int msk = 1; msk <= 8; msk <<= 1) sm += __shfl_xor(sm, msk, 64);
      float inv = 1.0f / sm;
      int row = m0 + mw + mt * 16 + quad * 4 + r;
      int b = row >> 10, t = row & 1023;
      size_t base = (((size_t)b * NH + h) * TT + t) * DH;
      float e[4] = {e0 * inv, e1 * inv, e2 * inv, e3 * inv};
      if (tensor == 2) {
#pragma unroll
        for (int c = 0; c < 4; ++c) vs[base + l16 + c * 16] = e[c];
      } else {
        unsigned short* oh = tensor ? kh : qh;
        unsigned short* ol = tensor ? kl : ql;
#pragma unroll
        for (int c = 0; c < 4; ++c) {
          unsigned short hh = f2bf(e[c]);
          oh[base + l16 + c * 16] = hh;
          ol[base + l16 + c * 16] = f2bf(e[c] - bf2f(hh));
        }
      }
    }
  }
}

// ---------------------------------------------------------------------------
// P3: transpose + split V: vs [z][t][d] fp32 -> vth/vtl [z][d][t] bf16
// (PV MFMA B-operand needs k(=t... j)-contiguous per d row).
// ---------------------------------------------------------------------------
__global__ __launch_bounds__(256) void k_vsplit(
    const float* __restrict__ vs, unsigned short* __restrict__ vth,
    unsigned short* __restrict__ vtl)
{
  __shared__ float Vf[64][65];
  const int z = blockIdx.y, t0 = blockIdx.x * 64;
  const int tid = threadIdx.x;
#pragma unroll
  for (int it = 0; it < 4; ++it) {
    int tl = it * 16 + (tid >> 4);
    int d4 = (tid & 15) * 4;
    float4 v = *(const float4*)&vs[((size_t)z * TT + t0 + tl) * DH + d4];
    Vf[tl][d4 + 0] = v.x; Vf[tl][d4 + 1] = v.y;
    Vf[tl][d4 + 2] = v.z; Vf[tl][d4 + 3] = v.w;
  }
  __syncthreads();
#pragma unroll
  for (int it = 0; it < 8; ++it) {
    int d = it * 8 + (tid >> 5);
    int t = (tid & 31) * 2;
    float a0 = Vf[t][d], a1 = Vf[t + 1][d];
    unsigned short h0 = f2bf(a0), h1 = f2bf(a1);
    unsigned short l0 = f2bf(a0 - bf2f(h0)), l1 = f2bf(a1 - bf2f(h1));
    size_t o = ((size_t)z * DH + d) * TT + t0 + t;
    ushort2 hh; hh.x = h0; hh.y = h1;
    ushort2 ll; ll.x = l0; ll.y = l1;
    *(ushort2*)&vth[o] = hh;
    *(ushort2*)&vtl[o] = ll;
  }
}

// ---------------------------------------------------------------------------
// K2: scores via bf16x3 MFMA. One wave per lower-tri 64x64 tile; operands
// read straight from global (both q and k are k(=d)-contiguous). Full tiles
// stored (diag-tile upper garbage is finite and masked downstream).
// ---------------------------------------------------------------------------
__global__ __launch_bounds__(256) void k_qk(
    const unsigned short* __restrict__ qh, const unsigned short* __restrict__ ql,
    const unsigned short* __restrict__ kh, const unsigned short* __restrict__ kl,
    float* __restrict__ A)
{
  const int tid = threadIdx.x;
  const int gid = blockIdx.x * 4 + (tid >> 6);
  const int z = gid / 136;
  const int lx = gid - z * 136;
  int ti = (int)((sqrtf(8.0f * lx + 1.0f) - 1.0f) * 0.5f);
  while ((ti + 1) * (ti + 2) / 2 <= lx) ++ti;
  while (ti * (ti + 1) / 2 > lx) --ti;
  const int tj = lx - ti * (ti + 1) / 2;
  const int i0 = ti * 64, j0 = tj * 64;
  const int lane = tid & 63;
  const int quad = lane >> 4, l16 = lane & 15;
  const size_t zb = (size_t)z * TT * DH;

  short8 fbh[4][2], fbl[4][2];
#pragma unroll
  for (int nt = 0; nt < 4; ++nt)
#pragma unroll
    for (int ks = 0; ks < 2; ++ks) {
      size_t o = zb + (size_t)(j0 + nt * 16 + l16) * DH + ks * 32 + quad * 8;
      fbh[nt][ks] = *(const short8*)&kh[o];
      fbl[nt][ks] = *(const short8*)&kl[o];
    }

  f4 acc[4][4] = {};
#pragma unroll
  for (int mt = 0; mt < 4; ++mt) {
    short8 fah[2], fal[2];
#pragma unroll
    for (int ks = 0; ks < 2; ++ks) {
      size_t o = zb + (size_t)(i0 + mt * 16 + l16) * DH + ks * 32 + quad * 8;
      fah[ks] = *(const short8*)&qh[o];
      fal[ks] = *(const short8*)&ql[o];
    }
#pragma unroll
    for (int nt = 0; nt < 4; ++nt)
#pragma unroll
      for (int ks = 0; ks < 2; ++ks) {
        acc[mt][nt] = __builtin_amdgcn_mfma_f32_16x16x32_bf16(fah[ks], fbh[nt][ks], acc[mt][nt], 0, 0, 0);
        acc[mt][nt] = __builtin_amdgcn_mfma_f32_16x16x32_bf16(fah[ks], fbl[nt][ks], acc[mt][nt], 0, 0, 0);
        acc[mt][nt] = __builtin_amdgcn_mfma_f32_16x16x32_bf16(fal[ks], fbh[nt][ks], acc[mt][nt], 0, 0, 0);
      }
  }

  float* Ab = A + (size_t)z * TT * TT;
#pragma unroll
  for (int mt = 0; mt < 4; ++mt)
#pragma unroll
    for (int nt = 0; nt < 4; ++nt)
#pragma unroll
      for (int r = 0; r < 4; ++r)
        Ab[(size_t)(i0 + mt * 16 + quad * 4 + r) * TT + j0 + nt * 16 + l16] = acc[mt][nt][r];
}

// ---------------------------------------------------------------------------
// K3: diagonal run-length scan, chunked-parallel + work-balanced pairing:
// block handles groups (p, 15-p) -> every block scans exactly 1088 rows.
// ---------------------------------------------------------------------------
__global__ __launch_bounds__(512) void k_scan(float* __restrict__ A)
{
  __shared__ float Ssum[8][64];
  __shared__ float Gmax[8][64];
  const int z = blockIdx.y;
  const int lane = threadIdx.x & 63;
  const int w = threadIdx.x >> 6;
  float* __restrict__ Ab = A + (size_t)z * TT * TT;

  for (int g = 0; g < 2; ++g) {
    const int xb = g ? (15 - blockIdx.x) : blockIdx.x;
    const int dbase = xb * 64;
    const int d = dbase + lane;
    const int R = TT - dbase;
    const int L = R >> 3;
    const int r0 = dbase + w * L;

    float S = 0.0f;
#pragma unroll 8
    for (int t = 0; t < L; ++t) {
      int i = r0 + t;
      size_t idx = (i >= d) ? ((size_t)i * (TT + 1) - d) : 0;
      float s0 = Ab[idx];
      S += (i >= d) ? s0 : 0.0f;
    }
    Ssum[w][lane] = S;
    __syncthreads();

    float cs_in = 0.0f;
    for (int ww = 0; ww < w; ++ww) cs_in += Ssum[ww][lane];

    float lcs = 0.0f, gm = 0.0f;
#pragma unroll 8
    for (int t = 0; t < L; ++t) {
      int i = r0 + t;
      size_t idx = (i >= d) ? ((size_t)i * (TT + 1) - d) : 0;
      float s0 = Ab[idx];
      float s = (i >= d) ? s0 : 0.0f;
      lcs += s;
      float cs = cs_in + lcs;
      gm = fmaxf(gm, cs * (1.0f - s));
    }
    Gmax[w][lane] = gm;
    __syncthreads();

    float m = 0.0f;
    for (int ww = 0; ww < w; ++ww) m = fmaxf(m, Gmax[ww][lane]);

    lcs = 0.0f;
#pragma unroll 8
    for (int t = 0; t < L; ++t) {
      int i = r0 + t;
      bool ok = (i >= d);
      size_t idx = ok ? ((size_t)i * (TT + 1) - d) : 0;
      float s0 = Ab[idx];
      float s = ok ? s0 : 0.0f;
      lcs += s;
      float cs = cs_in + lcs;
      m = fmaxf(m, cs * (1.0f - s));
      if (ok) Ab[idx] = cs - m;
    }
    __syncthreads();
  }
}

// ---------------------------------------------------------------------------
// K4: fused flash-style softmax(P)·V. Wave-independent (no LDS/barriers):
// wave = 16-row band of a 64-row tile-row; pairing (ti, 15-ti) balances work.
// Online softmax with per-row stats in lanes l16 (P A-frag rows), shfl'd to
// acc rows (quad*4+r). bf16x3 P·V.  oatt [z][t][d] fp32.
// ---------------------------------------------------------------------------
__global__ __launch_bounds__(256) void k_pv(
    const float* __restrict__ A, const unsigned short* __restrict__ vth,
    const unsigned short* __restrict__ vtl, float* __restrict__ oatt)
{
  const int tid = threadIdx.x;
  const int z = blockIdx.y;
  const int w = tid >> 6;
  const int lane = tid & 63, quad = lane >> 4, l16 = lane & 15;
  const float* Az = A + (size_t)z * TT * TT;
  const unsigned short* vh = vth + (size_t)z * DH * TT;
  const unsigned short* vl = vtl + (size_t)z * DH * TT;

  for (int g = 0; g < 2; ++g) {
    const int ti = g ? (15 - blockIdx.x) : blockIdx.x;
    const int i0 = ti * 64;
    const int irow = i0 + w * 16 + l16;          // this lane's P-row
    const float invi = 1.0f / (float)(irow + 1);
    f4 acc[4] = {};
    float m_old = -3e38f, l_run = 0.0f;

    for (int jt = 0; jt <= ti; ++jt) {
      // load 16 score values (A-frag pattern: k = ks*32 + quad*8 + u)
      float sc[16];
#pragma unroll
      for (int ks = 0; ks < 2; ++ks) {
        f4 s0 = *(const f4*)&Az[(size_t)irow * TT + jt * 64 + ks * 32 + quad * 8];
        f4 s1 = *(const f4*)&Az[(size_t)irow * TT + jt * 64 + ks * 32 + quad * 8 + 4];
#pragma unroll
        for (int u = 0; u < 4; ++u) { sc[ks * 8 + u] = s0[u]; sc[ks * 8 + 4 + u] = s1[u]; }
      }
      // pos tie-break + causal mask
#pragma unroll
      for (int u = 0; u < 16; ++u) {
        int j = jt * 64 + (u >> 3) * 32 + quad * 8 + (u & 7);
        float v = sc[u] + (float)j * invi;
        sc[u] = (j <= irow) ? v : -3e38f;
      }
      // row max (rows live in l16; quads replicate via xor 16/32)
      float mt_ = sc[0];
#pragma unroll
      for (int u = 1; u < 16; ++u) mt_ = fmaxf(mt_, sc[u]);
      mt_ = fmaxf(mt_, __shfl_xor(mt_, 16, 64));
      mt_ = fmaxf(mt_, __shfl_xor(mt_, 32, 64));
      float m_new = fmaxf(m_old, mt_);
      float alpha = __expf((m_old - m_new) * INV_TAU);
      // exp + split to bf16 hi/lo + row sum
      unsigned short ph[16], pl[16];
      float ls = 0.0f;
#pragma unroll
      for (int u = 0; u < 16; ++u) {
        float pvv = __expf((sc[u] - m_new) * INV_TAU);
        unsigned short hh = f2bf(pvv);
        ph[u] = hh; pl[u] = f2bf(pvv - bf2f(hh));
        ls += pvv;
      }
      ls += __shfl_xor(ls, 16, 64);
      ls += __shfl_xor(ls, 32, 64);
      l_run = l_run * alpha + ls;
      m_old = m_new;
      // rescale acc (acc rows = quad*4+r -> fetch that row's alpha)
#pragma unroll
      for (int r = 0; r < 4; ++r) {
        float ar = __shfl(alpha, quad * 4 + r, 64);
#pragma unroll
        for (int nt = 0; nt < 4; ++nt) acc[nt][r] *= ar;
      }
      // MFMA: P(bf16x2) x V(bf16x2), x3 terms
#pragma unroll
      for (int ks = 0; ks < 2; ++ks) {
        short8 pah, pal;
#pragma unroll
        for (int u = 0; u < 8; ++u) { pah[u] = (short)ph[ks * 8 + u]; pal[u] = (short)pl[ks * 8 + u]; }
#pragma unroll
        for (int nt = 0; nt < 4; ++nt) {
          size_t vo = (size_t)(nt * 16 + l16) * TT + jt * 64 + ks * 32 + quad * 8;
          short8 fvh = *(const short8*)&vh[vo];
          short8 fvl = *(const short8*)&vl[vo];
          acc[nt] = __builtin_amdgcn_mfma_f32_16x16x32_bf16(pah, fvh, acc[nt], 0, 0, 0);
          acc[nt] = __builtin_amdgcn_mfma_f32_16x16x32_bf16(pah, fvl, acc[nt], 0, 0, 0);
          acc[nt] = __builtin_amdgcn_mfma_f32_16x16x32_bf16(pal, fvh, acc[nt], 0, 0, 0);
        }
      }
    }
    // epilogue: normalize by row sum and store
#pragma unroll
    for (int r = 0; r < 4; ++r) {
      float lr = __shfl(l_run, quad * 4 + r, 64);
      float inv = 1.0f / lr;
      int orow = i0 + w * 16 + quad * 4 + r;
#pragma unroll
      for (int nt = 0; nt < 4; ++nt)
        oatt[((size_t)z * TT + orow) * DH + nt * 16 + l16] = acc[nt][r] * inv;
    }
  }
}

// ---------------------------------------------------------------------------
// K6: per-head output projection.
// ---------------------------------------------------------------------------
__global__ __launch_bounds__(256) void k_oproj(
    const float* __restrict__ oatt, const float* __restrict__ wo,
    float* __restrict__ out)
{
  __shared__ float Wl[64][64];
  __shared__ float Ol[4][64];
  const int z = blockIdx.y;
  const int t0 = blockIdx.x * 4;
  const int b = z >> 3, h = z & 7;
  const int tid = threadIdx.x;
  const float* wb = wo + (size_t)h * 64 * 64;
#pragma unroll
  for (int u = 0; u < 4; ++u) {
    int q = tid + 256 * u;
    int dd = q >> 4, e4 = (q & 15) * 4;
    *(float4*)&Wl[dd][e4] = *(const float4*)&wb[(size_t)dd * 64 + e4];
  }
  {
    int r = tid >> 6, dd = tid & 63;
    Ol[r][dd] = oatt[((size_t)z * TT + t0 + r) * DH + dd];
  }
  __syncthreads();
  const int r = tid >> 6, e = tid & 63;
  float acc = 0.0f;
#pragma unroll
  for (int d = 0; d < 64; ++d) acc += Ol[r][d] * Wl[d][e];
  out[((size_t)b * TT + t0 + r) * DD + h * 64 + e] = acc;
}

// ---------------------------------------------------------------------------
// ws layout (<=164 MB):
//  [0,4)   qh     (later: oatt overwrites [0,8) after qk consumed q/k)
//  [4,8)   ql
//  [8,12)  kh
//  [12,16) kl
//  [16,24) vs fp32
//  [24,28) vth    [28,32) vtl
//  [33,161) A     ([33,41) doubles as xh/xl before k_qk overwrites it)
//  [161,162.5) wth  [162.5,164) wtl
// ---------------------------------------------------------------------------
extern "C" void kernel_launch(void* const* d_in, const int* in_sizes, int n_in,
                              void* d_out, int out_size, void* d_ws, size_t ws_size,
                              hipStream_t stream)
{
  (void)in_sizes; (void)n_in; (void)out_size; (void)ws_size;
  const float* x  = (const float*)d_in[0];
  const float* wq = (const float*)d_in[1];
  const float* wk = (const float*)d_in[2];
  const float* wv = (const float*)d_in[3];
  const float* wo = (const float*)d_in[4];
  float* out = (float*)d_out;

  char* ws = (char*)d_ws;
  const size_t MB = 1024 * 1024;
  unsigned short* qh = (unsigned short*)(ws);
  unsigned short* ql = (unsigned short*)(ws + 4 * MB);
  unsigned short* kh = (unsigned short*)(ws + 8 * MB);
  unsigned short* kl = (unsigned short*)(ws + 12 * MB);
  float*          vs = (float*)(ws + 16 * MB);
  unsigned short* vth = (unsigned short*)(ws + 24 * MB);
  unsigned short* vtl = (unsigned short*)(ws + 28 * MB);
  float*          oatt = (float*)(ws);                    // aliases qh/ql (dead)
  float*          A  = (float*)(ws + 33 * MB);
  unsigned short* xh = (unsigned short*)(ws + 33 * MB);   // aliases A[z<2] (dead by k_qk)
  unsigned short* xl = (unsigned short*)(ws + 37 * MB);
  unsigned short* wth = (unsigned short*)(ws + 161 * MB);
  unsigned short* wtl = (unsigned short*)(ws + 161 * MB + 1536 * 1024);

  hipLaunchKernelGGL(k_split_x, dim3(2048), dim3(256), 0, stream, x, xh, xl);
  hipLaunchKernelGGL(k_split_wt, dim3(8, 8, 3), dim3(256), 0, stream,
                     wq, wk, wv, wth, wtl);
  hipLaunchKernelGGL(k_proj_mfma, dim3(12, 32), dim3(256), 0, stream,
                     xh, xl, wth, wtl, qh, ql, kh, kl, vs);
  hipLaunchKernelGGL(k_vsplit, dim3(16, 32), dim3(256), 0, stream, vs, vth, vtl);
  hipLaunchKernelGGL(k_qk, dim3(1088), dim3(256), 0, stream, qh, ql, kh, kl, A);
  hipLaunchKernelGGL(k_scan, dim3(8, 32), dim3(512), 0, stream, A);
  hipLaunchKernelGGL(k_pv, dim3(8, 32), dim3(256), 0, stream, A, vth, vtl, oatt);
  hipLaunchKernelGGL(k_oproj, dim3(256, 32), dim3(256), 0, stream,
                     oatt, wo, out);
}

// Round 6
// 259.843 us; speedup vs baseline: 1.7308x; 1.0745x over previous
//
#include <hip/hip_runtime.h>
#include <math.h>

#define BB    4
#define TT    1024
#define DD    512
#define NH    8
#define DH    64
#define BH    32          // BB*NH
#define INV_TAU 10.0f

typedef __attribute__((ext_vector_type(8))) short short8;
typedef __attribute__((ext_vector_type(4))) float f4;

__device__ inline unsigned short f2bf(float f) {
  unsigned u = __float_as_uint(f);
  u += 0x7FFFu + ((u >> 16) & 1u);        // round-to-nearest-even
  return (unsigned short)(u >> 16);
}
__device__ inline float bf2f(unsigned short h) {
  return __uint_as_float(((unsigned)h) << 16);
}

// ---------------------------------------------------------------------------
// P1: split x (fp32 [4096][512]) into bf16 hi/lo planes (same layout).
// ---------------------------------------------------------------------------
__global__ __launch_bounds__(256) void k_split_x(
    const float* __restrict__ x, unsigned short* __restrict__ xh,
    unsigned short* __restrict__ xl)
{
  const int i = (blockIdx.x * 256 + threadIdx.x) * 4;
  float4 v = *(const float4*)&x[i];
  ushort4 h, l;
  h.x = f2bf(v.x); l.x = f2bf(v.x - bf2f(h.x));
  h.y = f2bf(v.y); l.y = f2bf(v.y - bf2f(h.y));
  h.z = f2bf(v.z); l.z = f2bf(v.z - bf2f(h.z));
  h.w = f2bf(v.w); l.w = f2bf(v.w - bf2f(h.w));
  *(ushort4*)&xh[i] = h;
  *(ushort4*)&xl[i] = l;
}

// ---------------------------------------------------------------------------
// P2: transpose + split W -> wth/wtl [1536][512] bf16, k-contiguous rows.
// ---------------------------------------------------------------------------
__global__ __launch_bounds__(256) void k_split_wt(
    const float* __restrict__ wq, const float* __restrict__ wk,
    const float* __restrict__ wv, unsigned short* __restrict__ wth,
    unsigned short* __restrict__ wtl)
{
  __shared__ float Wf[64][65];
  const int ten = blockIdx.z;
  const float* W = (ten == 0) ? wq : ((ten == 1) ? wk : wv);
  const int n0 = blockIdx.x * 64, k0 = blockIdx.y * 64;
  const int tid = threadIdx.x;
#pragma unroll
  for (int p = 0; p < 4; ++p) {
    int kk = p * 16 + (tid >> 4);
    int nn = (tid & 15) * 4;
    float4 v = *(const float4*)&W[(size_t)(k0 + kk) * 512 + n0 + nn];
    Wf[kk][nn + 0] = v.x; Wf[kk][nn + 1] = v.y;
    Wf[kk][nn + 2] = v.z; Wf[kk][nn + 3] = v.w;
  }
  __syncthreads();
  const int n = tid >> 2, kq = tid & 3;
  size_t base = ((size_t)(ten * 512 + n0 + n)) * 512 + k0 + kq * 16;
#pragma unroll
  for (int jj = 0; jj < 4; ++jj) {
    ushort4 h, l;
    float f0 = Wf[kq * 16 + jj * 4 + 0][n];
    float f1 = Wf[kq * 16 + jj * 4 + 1][n];
    float f2 = Wf[kq * 16 + jj * 4 + 2][n];
    float f3 = Wf[kq * 16 + jj * 4 + 3][n];
    h.x = f2bf(f0); l.x = f2bf(f0 - bf2f(h.x));
    h.y = f2bf(f1); l.y = f2bf(f1 - bf2f(h.y));
    h.z = f2bf(f2); l.z = f2bf(f2 - bf2f(h.z));
    h.w = f2bf(f3); l.w = f2bf(f3 - bf2f(h.w));
    *(ushort4*)&wth[base + jj * 4] = h;
    *(ushort4*)&wtl[base + jj * 4] = l;
  }
}

// ---------------------------------------------------------------------------
// K1: QKV projection via bf16x3 MFMA + fused per-head softmax.
// q,k heads: emitted as bf16 hi/lo planes [z][t][d] (feeds MFMA qk).
// v heads:  emitted fp32 [z][t][d] (k_vsplit transposes+splits for pv).
// ---------------------------------------------------------------------------
__global__ __launch_bounds__(256) void k_proj_mfma(
    const unsigned short* __restrict__ xh, const unsigned short* __restrict__ xl,
    const unsigned short* __restrict__ wth, const unsigned short* __restrict__ wtl,
    unsigned short* __restrict__ qh, unsigned short* __restrict__ ql,
    unsigned short* __restrict__ kh, unsigned short* __restrict__ kl,
    float* __restrict__ vs)
{
  __shared__ unsigned short Ah[128][40];
  __shared__ unsigned short Al[128][40];
  __shared__ unsigned short Bh[128][40];
  __shared__ unsigned short Bl[128][40];
  const int tid = threadIdx.x;
  const int n0g = blockIdx.x * 128;
  const int m0 = blockIdx.y * 128;
  const int w = tid >> 6, lane = tid & 63;
  const int mw = (w & 1) * 64, nw = (w >> 1) * 64;
  const int quad = lane >> 4, l16 = lane & 15;
  const int srow = tid >> 2;
  const int sk = (tid & 3) * 8;

  f4 acc[4][4] = {};

  for (int k0 = 0; k0 < DD; k0 += 32) {
    short8 a0 = *(const short8*)&xh[(size_t)(m0 + srow) * DD + k0 + sk];
    short8 a1 = *(const short8*)&xh[(size_t)(m0 + 64 + srow) * DD + k0 + sk];
    short8 a2 = *(const short8*)&xl[(size_t)(m0 + srow) * DD + k0 + sk];
    short8 a3 = *(const short8*)&xl[(size_t)(m0 + 64 + srow) * DD + k0 + sk];
    short8 b0 = *(const short8*)&wth[(size_t)(n0g + srow) * DD + k0 + sk];
    short8 b1 = *(const short8*)&wth[(size_t)(n0g + 64 + srow) * DD + k0 + sk];
    short8 b2 = *(const short8*)&wtl[(size_t)(n0g + srow) * DD + k0 + sk];
    short8 b3 = *(const short8*)&wtl[(size_t)(n0g + 64 + srow) * DD + k0 + sk];
    *(short8*)&Ah[srow][sk] = a0;  *(short8*)&Ah[64 + srow][sk] = a1;
    *(short8*)&Al[srow][sk] = a2;  *(short8*)&Al[64 + srow][sk] = a3;
    *(short8*)&Bh[srow][sk] = b0;  *(short8*)&Bh[64 + srow][sk] = b1;
    *(short8*)&Bl[srow][sk] = b2;  *(short8*)&Bl[64 + srow][sk] = b3;
    __syncthreads();

    short8 fbh[4], fbl[4];
#pragma unroll
    for (int nt = 0; nt < 4; ++nt) {
      fbh[nt] = *(const short8*)&Bh[nw + nt * 16 + l16][quad * 8];
      fbl[nt] = *(const short8*)&Bl[nw + nt * 16 + l16][quad * 8];
    }
#pragma unroll
    for (int mt = 0; mt < 4; ++mt) {
      short8 fah = *(const short8*)&Ah[mw + mt * 16 + l16][quad * 8];
      short8 fal = *(const short8*)&Al[mw + mt * 16 + l16][quad * 8];
#pragma unroll
      for (int nt = 0; nt < 4; ++nt) {
        acc[mt][nt] = __builtin_amdgcn_mfma_f32_16x16x32_bf16(fah, fbh[nt], acc[mt][nt], 0, 0, 0);
        acc[mt][nt] = __builtin_amdgcn_mfma_f32_16x16x32_bf16(fah, fbl[nt], acc[mt][nt], 0, 0, 0);
        acc[mt][nt] = __builtin_amdgcn_mfma_f32_16x16x32_bf16(fal, fbh[nt], acc[mt][nt], 0, 0, 0);
      }
    }
    __syncthreads();
  }

  const int tensor = n0g >> 9;
  const int ncol = (n0g & 511) + nw;
  const int h = ncol >> 6;
#pragma unroll
  for (int mt = 0; mt < 4; ++mt) {
#pragma unroll
    for (int r = 0; r < 4; ++r) {
      float v0 = acc[mt][0][r], v1 = acc[mt][1][r];
      float v2 = acc[mt][2][r], v3 = acc[mt][3][r];
      float mx = fmaxf(fmaxf(v0, v1), fmaxf(v2, v3));
#pragma unroll
      for (int msk = 1; msk <= 8; msk <<= 1) mx = fmaxf(mx, __shfl_xor(mx, msk, 64));
      float e0 = __expf((v0 - mx) * INV_TAU);
      float e1 = __expf((v1 - mx) * INV_TAU);
      float e2 = __expf((v2 - mx) * INV_TAU);
      float e3 = __expf((v3 - mx) * INV_TAU);
      float sm = e0 + e1 + e2 + e3;
#pragma unroll
      for (int msk = 1; msk <= 8; msk <<= 1) sm += __shfl_xor(sm, msk, 64);
      float inv = 1.0f / sm;
      int row = m0 + mw + mt * 16 + quad * 4 + r;
      int b = row >> 10, t = row & 1023;
      size_t base = (((size_t)b * NH + h) * TT + t) * DH;
      float e[4] = {e0 * inv, e1 * inv, e2 * inv, e3 * inv};
      if (tensor == 2) {
#pragma unroll
        for (int c = 0; c < 4; ++c) vs[base + l16 + c * 16] = e[c];
      } else {
        unsigned short* oh = tensor ? kh : qh;
        unsigned short* ol = tensor ? kl : ql;
#pragma unroll
        for (int c = 0; c < 4; ++c) {
          unsigned short hh = f2bf(e[c]);
          oh[base + l16 + c * 16] = hh;
          ol[base + l16 + c * 16] = f2bf(e[c] - bf2f(hh));
        }
      }
    }
  }
}

// ---------------------------------------------------------------------------
// P3: transpose + split V: vs [z][t][d] fp32 -> vth/vtl [z][d][t] bf16.
// ---------------------------------------------------------------------------
__global__ __launch_bounds__(256) void k_vsplit(
    const float* __restrict__ vs, unsigned short* __restrict__ vth,
    unsigned short* __restrict__ vtl)
{
  __shared__ float Vf[64][65];
  const int z = blockIdx.y, t0 = blockIdx.x * 64;
  const int tid = threadIdx.x;
#pragma unroll
  for (int it = 0; it < 4; ++it) {
    int tl = it * 16 + (tid >> 4);
    int d4 = (tid & 15) * 4;
    float4 v = *(const float4*)&vs[((size_t)z * TT + t0 + tl) * DH + d4];
    Vf[tl][d4 + 0] = v.x; Vf[tl][d4 + 1] = v.y;
    Vf[tl][d4 + 2] = v.z; Vf[tl][d4 + 3] = v.w;
  }
  __syncthreads();
#pragma unroll
  for (int it = 0; it < 8; ++it) {
    int d = it * 8 + (tid >> 5);
    int t = (tid & 31) * 2;
    float a0 = Vf[t][d], a1 = Vf[t + 1][d];
    unsigned short h0 = f2bf(a0), h1 = f2bf(a1);
    unsigned short l0 = f2bf(a0 - bf2f(h0)), l1 = f2bf(a1 - bf2f(h1));
    size_t o = ((size_t)z * DH + d) * TT + t0 + t;
    ushort2 hh; hh.x = h0; hh.y = h1;
    ushort2 ll; ll.x = l0; ll.y = l1;
    *(ushort2*)&vth[o] = hh;
    *(ushort2*)&vtl[o] = ll;
  }
}

// ---------------------------------------------------------------------------
// K2: scores via bf16x3 MFMA. One wave per lower-tri 64x64 tile.
// ---------------------------------------------------------------------------
__global__ __launch_bounds__(256) void k_qk(
    const unsigned short* __restrict__ qh, const unsigned short* __restrict__ ql,
    const unsigned short* __restrict__ kh, const unsigned short* __restrict__ kl,
    float* __restrict__ A)
{
  const int tid = threadIdx.x;
  const int gid = blockIdx.x * 4 + (tid >> 6);
  const int z = gid / 136;
  const int lx = gid - z * 136;
  int ti = (int)((sqrtf(8.0f * lx + 1.0f) - 1.0f) * 0.5f);
  while ((ti + 1) * (ti + 2) / 2 <= lx) ++ti;
  while (ti * (ti + 1) / 2 > lx) --ti;
  const int tj = lx - ti * (ti + 1) / 2;
  const int i0 = ti * 64, j0 = tj * 64;
  const int lane = tid & 63;
  const int quad = lane >> 4, l16 = lane & 15;
  const size_t zb = (size_t)z * TT * DH;

  short8 fbh[4][2], fbl[4][2];
#pragma unroll
  for (int nt = 0; nt < 4; ++nt)
#pragma unroll
    for (int ks = 0; ks < 2; ++ks) {
      size_t o = zb + (size_t)(j0 + nt * 16 + l16) * DH + ks * 32 + quad * 8;
      fbh[nt][ks] = *(const short8*)&kh[o];
      fbl[nt][ks] = *(const short8*)&kl[o];
    }

  f4 acc[4][4] = {};
#pragma unroll
  for (int mt = 0; mt < 4; ++mt) {
    short8 fah[2], fal[2];
#pragma unroll
    for (int ks = 0; ks < 2; ++ks) {
      size_t o = zb + (size_t)(i0 + mt * 16 + l16) * DH + ks * 32 + quad * 8;
      fah[ks] = *(const short8*)&qh[o];
      fal[ks] = *(const short8*)&ql[o];
    }
#pragma unroll
    for (int nt = 0; nt < 4; ++nt)
#pragma unroll
      for (int ks = 0; ks < 2; ++ks) {
        acc[mt][nt] = __builtin_amdgcn_mfma_f32_16x16x32_bf16(fah[ks], fbh[nt][ks], acc[mt][nt], 0, 0, 0);
        acc[mt][nt] = __builtin_amdgcn_mfma_f32_16x16x32_bf16(fah[ks], fbl[nt][ks], acc[mt][nt], 0, 0, 0);
        acc[mt][nt] = __builtin_amdgcn_mfma_f32_16x16x32_bf16(fal[ks], fbh[nt][ks], acc[mt][nt], 0, 0, 0);
      }
  }

  float* Ab = A + (size_t)z * TT * TT;
#pragma unroll
  for (int mt = 0; mt < 4; ++mt)
#pragma unroll
    for (int nt = 0; nt < 4; ++nt)
#pragma unroll
      for (int r = 0; r < 4; ++r)
        Ab[(size_t)(i0 + mt * 16 + quad * 4 + r) * TT + j0 + nt * 16 + l16] = acc[mt][nt][r];
}

// ---------------------------------------------------------------------------
// K3: diagonal run-length scan, chunked-parallel, 16 chunks (1024 thr),
// paired groups (x, 15-x) with phases interleaved between barriers:
// A0+A1 | sync | C0+C1 | sync | E0+E1.  16 waves/CU, 3 barriers.
// ---------------------------------------------------------------------------
__global__ __launch_bounds__(1024) void k_scan(float* __restrict__ A)
{
  __shared__ float Ssum[2][16][64];
  __shared__ float Gmax[2][16][64];
  const int z = blockIdx.y;
  const int lane = threadIdx.x & 63;
  const int w = threadIdx.x >> 6;          // chunk 0..15
  float* __restrict__ Ab = A + (size_t)z * TT * TT;

  const int db0 = blockIdx.x * 64;
  const int db1 = (15 - blockIdx.x) * 64;
  const int d0 = db0 + lane, d1 = db1 + lane;
  const int L0 = (TT - db0) >> 4, L1 = (TT - db1) >> 4;
  const int r00 = db0 + w * L0, r01 = db1 + w * L1;

  // Phase A: chunk sums, both groups
  float S0 = 0.0f, S1 = 0.0f;
#pragma unroll 8
  for (int t = 0; t < L0; ++t) {
    int i = r00 + t;
    size_t idx = (i >= d0) ? ((size_t)i * (TT + 1) - d0) : 0;
    float s = Ab[idx];
    S0 += (i >= d0) ? s : 0.0f;
  }
#pragma unroll 8
  for (int t = 0; t < L1; ++t) {
    int i = r01 + t;
    size_t idx = (i >= d1) ? ((size_t)i * (TT + 1) - d1) : 0;
    float s = Ab[idx];
    S1 += (i >= d1) ? s : 0.0f;
  }
  Ssum[0][w][lane] = S0;
  Ssum[1][w][lane] = S1;
  __syncthreads();

  float ci0 = 0.0f, ci1 = 0.0f;
  for (int ww = 0; ww < w; ++ww) {
    ci0 += Ssum[0][ww][lane];
    ci1 += Ssum[1][ww][lane];
  }

  // Phase C: chunk g-max, both groups
  {
    float lcs = 0.0f, gm = 0.0f;
#pragma unroll 8
    for (int t = 0; t < L0; ++t) {
      int i = r00 + t;
      size_t idx = (i >= d0) ? ((size_t)i * (TT + 1) - d0) : 0;
      float s0 = Ab[idx];
      float s = (i >= d0) ? s0 : 0.0f;
      lcs += s;
      gm = fmaxf(gm, (ci0 + lcs) * (1.0f - s));
    }
    Gmax[0][w][lane] = gm;
  }
  {
    float lcs = 0.0f, gm = 0.0f;
#pragma unroll 8
    for (int t = 0; t < L1; ++t) {
      int i = r01 + t;
      size_t idx = (i >= d1) ? ((size_t)i * (TT + 1) - d1) : 0;
      float s0 = Ab[idx];
      float s = (i >= d1) ? s0 : 0.0f;
      lcs += s;
      gm = fmaxf(gm, (ci1 + lcs) * (1.0f - s));
    }
    Gmax[1][w][lane] = gm;
  }
  __syncthreads();

  float m0 = 0.0f, m1 = 0.0f;
  for (int ww = 0; ww < w; ++ww) {
    m0 = fmaxf(m0, Gmax[0][ww][lane]);
    m1 = fmaxf(m1, Gmax[1][ww][lane]);
  }

  // Phase E: emit, both groups
  {
    float lcs = 0.0f, m = m0;
#pragma unroll 8
    for (int t = 0; t < L0; ++t) {
      int i = r00 + t;
      bool ok = (i >= d0);
      size_t idx = ok ? ((size_t)i * (TT + 1) - d0) : 0;
      float s0 = Ab[idx];
      float s = ok ? s0 : 0.0f;
      lcs += s;
      float cs = ci0 + lcs;
      m = fmaxf(m, cs * (1.0f - s));
      if (ok) Ab[idx] = cs - m;
    }
  }
  {
    float lcs = 0.0f, m = m1;
#pragma unroll 8
    for (int t = 0; t < L1; ++t) {
      int i = r01 + t;
      bool ok = (i >= d1);
      size_t idx = ok ? ((size_t)i * (TT + 1) - d1) : 0;
      float s0 = Ab[idx];
      float s = ok ? s0 : 0.0f;
      lcs += s;
      float cs = ci1 + lcs;
      m = fmaxf(m, cs * (1.0f - s));
      if (ok) Ab[idx] = cs - m;
    }
  }
}

// ---------------------------------------------------------------------------
// K4: fused flash-style softmax(P)·V. One wave per 16-row band (64-thr
// blocks, 2048 of them, heavy tiles first for dynamic balancing).
// ---------------------------------------------------------------------------
__global__ __launch_bounds__(64) void k_pv(
    const float* __restrict__ A, const unsigned short* __restrict__ vth,
    const unsigned short* __restrict__ vtl, float* __restrict__ oatt)
{
  const int lane = threadIdx.x;
  const int quad = lane >> 4, l16 = lane & 15;
  const int blk = blockIdx.x;              // 0..2047
  const int z = blk & 31;
  const int r = blk >> 5;                  // 0..63
  const int ti = 15 - (r >> 2);            // heavy (ti=15) first
  const int band = r & 3;
  const float* Az = A + (size_t)z * TT * TT;
  const unsigned short* vh = vth + (size_t)z * DH * TT;
  const unsigned short* vl = vtl + (size_t)z * DH * TT;

  const int i0 = ti * 64;
  const int irow = i0 + band * 16 + l16;   // this lane's P-row
  const float invi = 1.0f / (float)(irow + 1);
  f4 acc[4] = {};
  float m_old = -3e38f, l_run = 0.0f;

  for (int jt = 0; jt <= ti; ++jt) {
    float sc[16];
#pragma unroll
    for (int ks = 0; ks < 2; ++ks) {
      f4 s0 = *(const f4*)&Az[(size_t)irow * TT + jt * 64 + ks * 32 + quad * 8];
      f4 s1 = *(const f4*)&Az[(size_t)irow * TT + jt * 64 + ks * 32 + quad * 8 + 4];
#pragma unroll
      for (int u = 0; u < 4; ++u) { sc[ks * 8 + u] = s0[u]; sc[ks * 8 + 4 + u] = s1[u]; }
    }
#pragma unroll
    for (int u = 0; u < 16; ++u) {
      int j = jt * 64 + (u >> 3) * 32 + quad * 8 + (u & 7);
      float v = sc[u] + (float)j * invi;
      sc[u] = (j <= irow) ? v : -3e38f;
    }
    float mt_ = sc[0];
#pragma unroll
    for (int u = 1; u < 16; ++u) mt_ = fmaxf(mt_, sc[u]);
    mt_ = fmaxf(mt_, __shfl_xor(mt_, 16, 64));
    mt_ = fmaxf(mt_, __shfl_xor(mt_, 32, 64));
    float m_new = fmaxf(m_old, mt_);
    float alpha = __expf((m_old - m_new) * INV_TAU);
    unsigned short ph[16], pl[16];
    float ls = 0.0f;
#pragma unroll
    for (int u = 0; u < 16; ++u) {
      float pvv = __expf((sc[u] - m_new) * INV_TAU);
      unsigned short hh = f2bf(pvv);
      ph[u] = hh; pl[u] = f2bf(pvv - bf2f(hh));
      ls += pvv;
    }
    ls += __shfl_xor(ls, 16, 64);
    ls += __shfl_xor(ls, 32, 64);
    l_run = l_run * alpha + ls;
    m_old = m_new;
#pragma unroll
    for (int rr = 0; rr < 4; ++rr) {
      float ar = __shfl(alpha, quad * 4 + rr, 64);
#pragma unroll
      for (int nt = 0; nt < 4; ++nt) acc[nt][rr] *= ar;
    }
#pragma unroll
    for (int ks = 0; ks < 2; ++ks) {
      short8 pah, pal;
#pragma unroll
      for (int u = 0; u < 8; ++u) { pah[u] = (short)ph[ks * 8 + u]; pal[u] = (short)pl[ks * 8 + u]; }
#pragma unroll
      for (int nt = 0; nt < 4; ++nt) {
        size_t vo = (size_t)(nt * 16 + l16) * TT + jt * 64 + ks * 32 + quad * 8;
        short8 fvh = *(const short8*)&vh[vo];
        short8 fvl = *(const short8*)&vl[vo];
        acc[nt] = __builtin_amdgcn_mfma_f32_16x16x32_bf16(pah, fvh, acc[nt], 0, 0, 0);
        acc[nt] = __builtin_amdgcn_mfma_f32_16x16x32_bf16(pah, fvl, acc[nt], 0, 0, 0);
        acc[nt] = __builtin_amdgcn_mfma_f32_16x16x32_bf16(pal, fvh, acc[nt], 0, 0, 0);
      }
    }
  }
#pragma unroll
  for (int rr = 0; rr < 4; ++rr) {
    float lr = __shfl(l_run, quad * 4 + rr, 64);
    float inv = 1.0f / lr;
    int orow = i0 + band * 16 + quad * 4 + rr;
#pragma unroll
    for (int nt = 0; nt < 4; ++nt)
      oatt[((size_t)z * TT + orow) * DH + nt * 16 + l16] = acc[nt][rr] * inv;
  }
}

// ---------------------------------------------------------------------------
// K6: per-head output projection.
// ---------------------------------------------------------------------------
__global__ __launch_bounds__(256) void k_oproj(
    const float* __restrict__ oatt, const float* __restrict__ wo,
    float* __restrict__ out)
{
  __shared__ float Wl[64][64];
  __shared__ float Ol[4][64];
  const int z = blockIdx.y;
  const int t0 = blockIdx.x * 4;
  const int b = z >> 3, h = z & 7;
  const int tid = threadIdx.x;
  const float* wb = wo + (size_t)h * 64 * 64;
#pragma unroll
  for (int u = 0; u < 4; ++u) {
    int q = tid + 256 * u;
    int dd = q >> 4, e4 = (q & 15) * 4;
    *(float4*)&Wl[dd][e4] = *(const float4*)&wb[(size_t)dd * 64 + e4];
  }
  {
    int r = tid >> 6, dd = tid & 63;
    Ol[r][dd] = oatt[((size_t)z * TT + t0 + r) * DH + dd];
  }
  __syncthreads();
  const int r = tid >> 6, e = tid & 63;
  float acc = 0.0f;
#pragma unroll
  for (int d = 0; d < 64; ++d) acc += Ol[r][d] * Wl[d][e];
  out[((size_t)b * TT + t0 + r) * DD + h * 64 + e] = acc;
}

// ---------------------------------------------------------------------------
// ws layout (<=164 MB):
//  [0,4) qh  [4,8) ql  [8,12) kh  [12,16) kl   (oatt aliases [0,8) later)
//  [16,24) vs fp32   [24,28) vth  [28,32) vtl
//  [33,161) A        ([33,41) doubles as xh/xl before k_qk overwrites it)
//  [161,162.5) wth   [162.5,164) wtl
// ---------------------------------------------------------------------------
extern "C" void kernel_launch(void* const* d_in, const int* in_sizes, int n_in,
                              void* d_out, int out_size, void* d_ws, size_t ws_size,
                              hipStream_t stream)
{
  (void)in_sizes; (void)n_in; (void)out_size; (void)ws_size;
  const float* x  = (const float*)d_in[0];
  const float* wq = (const float*)d_in[1];
  const float* wk = (const float*)d_in[2];
  const float* wv = (const float*)d_in[3];
  const float* wo = (const float*)d_in[4];
  float* out = (float*)d_out;

  char* ws = (char*)d_ws;
  const size_t MB = 1024 * 1024;
  unsigned short* qh = (unsigned short*)(ws);
  unsigned short* ql = (unsigned short*)(ws + 4 * MB);
  unsigned short* kh = (unsigned short*)(ws + 8 * MB);
  unsigned short* kl = (unsigned short*)(ws + 12 * MB);
  float*          vs = (float*)(ws + 16 * MB);
  unsigned short* vth = (unsigned short*)(ws + 24 * MB);
  unsigned short* vtl = (unsigned short*)(ws + 28 * MB);
  float*          oatt = (float*)(ws);                    // aliases qh/ql (dead)
  float*          A  = (float*)(ws + 33 * MB);
  unsigned short* xh = (unsigned short*)(ws + 33 * MB);   // aliases A (dead by k_qk)
  unsigned short* xl = (unsigned short*)(ws + 37 * MB);
  unsigned short* wth = (unsigned short*)(ws + 161 * MB);
  unsigned short* wtl = (unsigned short*)(ws + 161 * MB + 1536 * 1024);

  hipLaunchKernelGGL(k_split_x, dim3(2048), dim3(256), 0, stream, x, xh, xl);
  hipLaunchKernelGGL(k_split_wt, dim3(8, 8, 3), dim3(256), 0, stream,
                     wq, wk, wv, wth, wtl);
  hipLaunchKernelGGL(k_proj_mfma, dim3(12, 32), dim3(256), 0, stream,
                     xh, xl, wth, wtl, qh, ql, kh, kl, vs);
  hipLaunchKernelGGL(k_vsplit, dim3(16, 32), dim3(256), 0, stream, vs, vth, vtl);
  hipLaunchKernelGGL(k_qk, dim3(1088), dim3(256), 0, stream, qh, ql, kh, kl, A);
  hipLaunchKernelGGL(k_scan, dim3(8, 32), dim3(1024), 0, stream, A);
  hipLaunchKernelGGL(k_pv, dim3(2048), dim3(64), 0, stream, A, vth, vtl, oatt);
  hipLaunchKernelGGL(k_oproj, dim3(256, 32), dim3(256), 0, stream,
                     oatt, wo, out);
}